// Round 6
// baseline (287.402 us; speedup 1.0000x reference)
//
#include <hip/hip_runtime.h>
#include <math.h>

#define NQC   2048
#define NKVC  2048
#define DIMC  256
// 1/sqrt(32) * log2(e): attention scale with exp->exp2 base change folded in
#define SCALEF 0.2550348810731232f

typedef short bfrag __attribute__((ext_vector_type(8)));   // 8 bf16 = 4 VGPRs
typedef float ffrag __attribute__((ext_vector_type(4)));   // MFMA C/D
typedef unsigned short us8 __attribute__((ext_vector_type(8)));

__device__ __forceinline__ float gelu_exact(float x) {
    return 0.5f * x * (1.0f + erff(x * 0.70710678118654752f));
}
__device__ __forceinline__ unsigned short f2bf(float f) {
    union { float f; unsigned u; } v; v.f = f;
    unsigned r = v.u + 0x7FFFu + ((v.u >> 16) & 1u);   // RNE
    return (unsigned short)(r >> 16);
}
__device__ __forceinline__ float bf2f(unsigned short u) {
    union { unsigned u; float f; } v; v.u = ((unsigned)u) << 16;
    return v.f;
}
__device__ __forceinline__ float fexp2(float x) {
    float r; asm("v_exp_f32 %0, %1" : "=v"(r) : "v"(x)); return r;
}
__device__ __forceinline__ unsigned cvt_pk_bf16(float lo, float hi) {
    unsigned r; asm("v_cvt_pk_bf16_f32 %0, %1, %2" : "=v"(r) : "v"(lo), "v"(hi));
    return r;
}

// ---------------- LN device body (one wave per row) ----------------
__device__ __forceinline__ void ln_row(
    const float* __restrict__ x, const float* __restrict__ g,
    const float* __restrict__ b, unsigned short* __restrict__ y, int row)
{
    int lane = threadIdx.x & 63;
    const float* xr = x + (size_t)row * DIMC + lane * 4;
    float4 vv = *(const float4*)xr;
    float s  = vv.x + vv.y + vv.z + vv.w;
    float sq = vv.x*vv.x + vv.y*vv.y + vv.z*vv.z + vv.w*vv.w;
    #pragma unroll
    for (int off = 32; off >= 1; off >>= 1) {
        s  += __shfl_xor(s, off);
        sq += __shfl_xor(sq, off);
    }
    float mean = s * (1.0f/DIMC);
    float inv  = rsqrtf(sq * (1.0f/DIMC) - mean*mean + 1e-5f);
    float4 gg = *(const float4*)(g + lane*4);
    float4 bb = *(const float4*)(b + lane*4);
    ushort4 o;
    o.x = f2bf((vv.x - mean) * inv * gg.x + bb.x);
    o.y = f2bf((vv.y - mean) * inv * gg.y + bb.y);
    o.z = f2bf((vv.z - mean) * inv * gg.z + bb.z);
    o.w = f2bf((vv.w - mean) * inv * gg.w + bb.w);
    *(ushort4*)(y + (size_t)row * DIMC + lane * 4) = o;
}

// ---------------- normalized A-fragment loader (LN fused into GEMM A-path) -----------
__device__ __forceinline__ void ln_frag(
    const float* __restrict__ xr, const float* __restrict__ lng,
    const float* __restrict__ lnb, int cc, float mean, float inv,
    us8& o0, us8& o1)
{
    float4 x0 = *(const float4*)(xr + cc);
    float4 x1 = *(const float4*)(xr + cc + 4);
    float4 x2 = *(const float4*)(xr + cc + 8);
    float4 x3 = *(const float4*)(xr + cc + 12);
    float4 g0 = *(const float4*)(lng + cc);
    float4 g1 = *(const float4*)(lng + cc + 4);
    float4 g2 = *(const float4*)(lng + cc + 8);
    float4 g3 = *(const float4*)(lng + cc + 12);
    float4 b0 = *(const float4*)(lnb + cc);
    float4 b1 = *(const float4*)(lnb + cc + 4);
    float4 b2 = *(const float4*)(lnb + cc + 8);
    float4 b3 = *(const float4*)(lnb + cc + 12);
    union { us8 v; unsigned short s[8]; } u0, u1;
    u0.s[0] = f2bf(((x0.x - mean) * inv) * g0.x + b0.x);
    u0.s[1] = f2bf(((x0.y - mean) * inv) * g0.y + b0.y);
    u0.s[2] = f2bf(((x0.z - mean) * inv) * g0.z + b0.z);
    u0.s[3] = f2bf(((x0.w - mean) * inv) * g0.w + b0.w);
    u0.s[4] = f2bf(((x1.x - mean) * inv) * g1.x + b1.x);
    u0.s[5] = f2bf(((x1.y - mean) * inv) * g1.y + b1.y);
    u0.s[6] = f2bf(((x1.z - mean) * inv) * g1.z + b1.z);
    u0.s[7] = f2bf(((x1.w - mean) * inv) * g1.w + b1.w);
    u1.s[0] = f2bf(((x2.x - mean) * inv) * g2.x + b2.x);
    u1.s[1] = f2bf(((x2.y - mean) * inv) * g2.y + b2.y);
    u1.s[2] = f2bf(((x2.z - mean) * inv) * g2.z + b2.z);
    u1.s[3] = f2bf(((x2.w - mean) * inv) * g2.w + b2.w);
    u1.s[4] = f2bf(((x3.x - mean) * inv) * g3.x + b3.x);
    u1.s[5] = f2bf(((x3.y - mean) * inv) * g3.y + b3.y);
    u1.s[6] = f2bf(((x3.z - mean) * inv) * g3.z + b3.z);
    u1.s[7] = f2bf(((x3.w - mean) * inv) * g3.w + b3.w);
    o0 = u0.v; o1 = u1.v;
}

// ---------------- packed prep: tiled-transpose weights + linear copies + LN(v) + bias folds
// blocks 0..351:   64x64 weight tiles, coalesced load -> LDS transpose -> coalesced store
// blocks 352..479: linear bf16 copies (projbf, projxbf)
// blocks 480..1503: LN(v) -> NVB
// blocks 1504..1505: folded biases
__global__ __launch_bounds__(256) void prep_w(
    const float* __restrict__ qkv, const float* __restrict__ knn,
    const float* __restrict__ proj, const float* __restrict__ merge,
    const float* __restrict__ caq, const float* __restrict__ knnx,
    const float* __restrict__ cakv, const float* __restrict__ projx,
    const float* __restrict__ mergex, const float* __restrict__ fc1,
    const float* __restrict__ fc2, unsigned short* __restrict__ dst,
    const float* __restrict__ vx, const float* __restrict__ vg,
    const float* __restrict__ vb, unsigned short* __restrict__ vy,
    const float* __restrict__ pb1, const float* __restrict__ mb1, float* __restrict__ bf1o,
    const float* __restrict__ pbx, const float* __restrict__ mbx, float* __restrict__ bfxo)
{
    __shared__ unsigned short T[64][72];
    int blk = blockIdx.x, tid = threadIdx.x;
    if (blk >= 1504) {
        // folded bias: bfold[m] = merge_b[m] + sum_k proj_b[k] * merge_w[k][m]
        const float* bp = (blk == 1504) ? pb1 : pbx;
        const float* Wm = (blk == 1504) ? merge : mergex;
        const float* bm = (blk == 1504) ? mb1 : mbx;
        float* o        = (blk == 1504) ? bf1o : bfxo;
        int m = tid;
        float acc = bm[m];
        for (int k = 0; k < 256; ++k) acc += bp[k] * Wm[(size_t)k * 256 + m];
        o[m] = acc;
        return;
    }
    if (blk >= 480) {   // LN(v): input-only dependency, hoisted to prep
        ln_row(vx, vg, vb, vy, (blk - 480) * 4 + (tid >> 6));
        return;
    }
    if (blk >= 352) {   // linear copies (already [k][n]-major in both layouts)
        int l = blk - 352;
        const float* s; unsigned short* d;
        if (l < 64) { s = proj;  d = dst + 327680; }
        else        { s = projx; d = dst + 851968; l -= 64; }
        int e = (l * 256 + tid) * 4;
        float4 v = *(const float4*)(s + e);
        ushort4 o;
        o.x = f2bf(v.x); o.y = f2bf(v.y); o.z = f2bf(v.z); o.w = f2bf(v.w);
        *(ushort4*)(d + e) = o;
        return;
    }
    // ---- 64x64 transpose tile: dst[n][k] <- src[k][n] (optionally minus src2, scaled)
    int t = blk;
    const float* src; const float* src2 = nullptr; int sN;
    unsigned short* dp; int dK; float scale = 1.0f; int n0, k0;
    if (t < 48)       { src = qkv;          sN = 768;  dp = dst;           dK = 256;
                        n0 = (t % 12) * 64; k0 = (t / 12) * 64; if (n0 < 256) scale = SCALEF; }
    else if (t < 64)  { int u = t - 48;  src = knn;          sN = 256; dp = dst + 196608; dK = 256;
                        n0 = (u & 3) * 64; k0 = (u >> 2) * 64; }             // knn lo -> WT1 rows 768..1024
    else if (t < 80)  { int u = t - 64;  src = knn + 65536;  src2 = knn; sN = 256; dp = dst + 262144; dK = 256;
                        n0 = (u & 3) * 64; k0 = (u >> 2) * 64; }             // knn hi-lo -> rows 1024..1280
    else if (t < 112) { int u = t - 80;  src = merge;        sN = 256; dp = dst + 393216; dK = 512;
                        n0 = (u & 3) * 64; k0 = (u >> 2) * 64; }
    else if (t < 128) { int u = t - 112; src = caq;          sN = 256; dp = dst + 524288; dK = 256;
                        n0 = (u & 3) * 64; k0 = (u >> 2) * 64; scale = SCALEF; }
    else if (t < 144) { int u = t - 128; src = knnx + 65536; src2 = knnx; sN = 256; dp = dst + 589824; dK = 256;
                        n0 = (u & 3) * 64; k0 = (u >> 2) * 64; }             // WT2 rows 256..512
    else if (t < 176) { int u = t - 144; src = cakv;         sN = 512; dp = dst + 655360; dK = 256;
                        n0 = (u & 7) * 64; k0 = (u >> 3) * 64; }
    else if (t < 192) { int u = t - 176; src = knnx;         sN = 256; dp = dst + 786432; dK = 256;
                        n0 = (u & 3) * 64; k0 = (u >> 2) * 64; }             // WT3 rows 512..768
    else if (t < 224) { int u = t - 192; src = mergex;       sN = 256; dp = dst + 917504; dK = 512;
                        n0 = (u & 3) * 64; k0 = (u >> 2) * 64; }
    else if (t < 288) { int u = t - 224; src = fc1;          sN = 1024; dp = dst + 1048576; dK = 256;
                        n0 = (u & 15) * 64; k0 = (u >> 4) * 64; }
    else              { int u = t - 288; src = fc2;          sN = 256; dp = dst + 1310720; dK = 1024;
                        n0 = (u & 3) * 64; k0 = (u >> 2) * 64; }
    int r = tid >> 2, c0 = (tid & 3) * 16;
    float va[16];
    {
        const float* sp = src + (size_t)(k0 + r) * sN + n0 + c0;
        float4 f0 = *(const float4*)(sp);
        float4 f1 = *(const float4*)(sp + 4);
        float4 f2 = *(const float4*)(sp + 8);
        float4 f3 = *(const float4*)(sp + 12);
        va[0]=f0.x; va[1]=f0.y; va[2]=f0.z;  va[3]=f0.w;
        va[4]=f1.x; va[5]=f1.y; va[6]=f1.z;  va[7]=f1.w;
        va[8]=f2.x; va[9]=f2.y; va[10]=f2.z; va[11]=f2.w;
        va[12]=f3.x; va[13]=f3.y; va[14]=f3.z; va[15]=f3.w;
        if (src2) {
            const float* s2 = src2 + (size_t)(k0 + r) * sN + n0 + c0;
            float4 h0 = *(const float4*)(s2);
            float4 h1 = *(const float4*)(s2 + 4);
            float4 h2 = *(const float4*)(s2 + 8);
            float4 h3 = *(const float4*)(s2 + 12);
            va[0]-=h0.x; va[1]-=h0.y; va[2]-=h0.z;  va[3]-=h0.w;
            va[4]-=h1.x; va[5]-=h1.y; va[6]-=h1.z;  va[7]-=h1.w;
            va[8]-=h2.x; va[9]-=h2.y; va[10]-=h2.z; va[11]-=h2.w;
            va[12]-=h3.x; va[13]-=h3.y; va[14]-=h3.z; va[15]-=h3.w;
        }
    }
    #pragma unroll
    for (int i = 0; i < 16; ++i) T[c0 + i][r] = f2bf(va[i] * scale);
    __syncthreads();
    {
        int n = tid >> 2, kk = (tid & 3) * 16;
        unsigned short* d = dp + (size_t)(n0 + n) * dK + k0 + kk;
        *(us8*)d       = *(const us8*)&T[n][kk];
        *(us8*)(d + 8) = *(const us8*)&T[n][kk + 8];
    }
}

// ---------------- bf16 MFMA GEMM body, 64x64 tile, BK=64 ----------------
// LNA: A is raw f32 [rows][256] + LN(g,b) fused at staging (two-pass row stats).
// VTM: whole 64x64 output tiles in cols [vlo, vlo+256) are V: transpose via LDS
// with key-permutation pos = ((k&15)<<2)|(k>>4), then coalesced b128 VT stores.
template<int ACT, int RESID, int OUTBF, int VTM, int LNA>
__device__ __forceinline__ void gemm_body(
    const unsigned short* __restrict__ A, int lda,
    const float* __restrict__ Af, const float* __restrict__ lng,
    const float* __restrict__ lnb,
    const unsigned short* __restrict__ Wt,
    const float* __restrict__ bias,
    const float* __restrict__ resid, int ldr,
    void* __restrict__ Cp, int ldc, int Kc, int row0, int col0,
    unsigned short (* __restrict__ Alds)[72],
    unsigned short (* __restrict__ Wlds)[72],
    unsigned short* __restrict__ vt, int vlo)
{
    const int tid = threadIdx.x;
    const int wid = tid >> 6, lane = tid & 63;
    const int lm = lane & 15, quad = lane >> 4;
    const int wr = wid >> 1, wc = wid & 1;
    const int ar = tid >> 2, ac = (tid & 3) * 16;
    float mean = 0.f, inv = 0.f;
    const float* xr = nullptr;
    if (LNA) {
        xr = Af + (size_t)(row0 + ar) * 256;
        float s = 0.f, sq = 0.f;
        int cb = (tid & 3) * 64;
        #pragma unroll
        for (int i = 0; i < 16; ++i) {
            float4 v = *(const float4*)(xr + cb + i * 4);
            s  += (v.x + v.y) + (v.z + v.w);
            sq += (v.x*v.x + v.y*v.y) + (v.z*v.z + v.w*v.w);
        }
        s  += __shfl_xor(s, 1);  s  += __shfl_xor(s, 2);
        sq += __shfl_xor(sq, 1); sq += __shfl_xor(sq, 2);
        mean = s * (1.0f/256.0f);
        inv  = rsqrtf(sq * (1.0f/256.0f) - mean*mean + 1e-5f);
    }
    const unsigned short* Ag = LNA ? nullptr : A + (size_t)(row0 + ar) * lda + ac;
    const unsigned short* Wg = Wt + (size_t)(col0 + ar) * Kc + ac;

    us8 a0, a1, w0, w1;
    if (LNA) ln_frag(xr, lng, lnb, ac, mean, inv, a0, a1);
    else { a0 = *(const us8*)Ag; a1 = *(const us8*)(Ag + 8); }
    w0 = *(const us8*)Wg;
    w1 = *(const us8*)(Wg + 8);

    ffrag acc[2][2];
    #pragma unroll
    for (int mi = 0; mi < 2; ++mi)
        #pragma unroll
        for (int ni = 0; ni < 2; ++ni)
            acc[mi][ni] = (ffrag){0.f, 0.f, 0.f, 0.f};

    for (int k0 = 0;;) {
        __syncthreads();
        *(us8*)&Alds[ar][ac]   = a0;
        *(us8*)&Alds[ar][ac+8] = a1;
        *(us8*)&Wlds[ar][ac]   = w0;
        *(us8*)&Wlds[ar][ac+8] = w1;
        __syncthreads();
        k0 += 64;
        if (k0 < Kc) {
            if (LNA) ln_frag(xr, lng, lnb, k0 + ac, mean, inv, a0, a1);
            else { a0 = *(const us8*)(Ag + k0); a1 = *(const us8*)(Ag + k0 + 8); }
            w0 = *(const us8*)(Wg + k0);
            w1 = *(const us8*)(Wg + k0 + 8);
        }
        #pragma unroll
        for (int kc = 0; kc < 2; ++kc) {
            bfrag af[2], bw[2];
            #pragma unroll
            for (int mi = 0; mi < 2; ++mi)
                af[mi] = *(const bfrag*)&Alds[wr*32 + mi*16 + lm][kc*32 + quad*8];
            #pragma unroll
            for (int ni = 0; ni < 2; ++ni)
                bw[ni] = *(const bfrag*)&Wlds[wc*32 + ni*16 + lm][kc*32 + quad*8];
            #pragma unroll
            for (int mi = 0; mi < 2; ++mi)
                #pragma unroll
                for (int ni = 0; ni < 2; ++ni)
                    acc[mi][ni] = __builtin_amdgcn_mfma_f32_16x16x32_bf16(
                        af[mi], bw[ni], acc[mi][ni], 0, 0, 0);
        }
        if (k0 >= Kc) break;
    }
    if (VTM && col0 >= vlo && col0 - vlo < 256) {
        // V tile: rows = keys (64, row0 64-aligned), cols = dims (64, 2 heads).
        __syncthreads();                          // all waves done reading Alds
        #pragma unroll
        for (int mi = 0; mi < 2; ++mi) {
            #pragma unroll
            for (int ni = 0; ni < 2; ++ni) {
                int lr = wr*32 + mi*16 + quad*4;
                int lc = wc*32 + ni*16 + lm;
                #pragma unroll
                for (int r = 0; r < 4; ++r) {
                    int k = lr + r;
                    Alds[lc][((k & 15) << 2) | (k >> 4)] = f2bf(acc[mi][ni][r]);
                }
            }
        }
        __syncthreads();
        int d = tid >> 2, p0 = (tid & 3) * 16;
        int cv = col0 - vlo + d, hh = cv >> 5, dd = cv & 31;
        int bq = row0 >> 11, kblk = (row0 & 2047) >> 6;
        unsigned short* vp = vt + (((size_t)(bq * 8 + hh) * 32 + dd) * 2048)
                                + kblk * 64 + p0;
        *(us8*)vp       = *(const us8*)&Alds[d][p0];
        *(us8*)(vp + 8) = *(const us8*)&Alds[d][p0 + 8];
        return;
    }
    #pragma unroll
    for (int mi = 0; mi < 2; ++mi) {
        #pragma unroll
        for (int ni = 0; ni < 2; ++ni) {
            int gr = row0 + wr*32 + mi*16 + quad*4;
            int gc = col0 + wc*32 + ni*16 + lm;
            float bv = bias ? bias[gc] : 0.f;
            #pragma unroll
            for (int r = 0; r < 4; ++r) {
                float o = acc[mi][ni][r] + bv;
                if (ACT == 1) o = gelu_exact(o);
                if (RESID) o += resid[(size_t)(gr + r) * ldr + gc];
                if (OUTBF) ((unsigned short*)Cp)[(size_t)(gr + r) * ldc + gc] = f2bf(o);
                else       ((float*)Cp)[(size_t)(gr + r) * ldc + gc] = o;
            }
        }
    }
}

// ---------------- qkv GEMM (LN(q) fused, V->VT redirect) + weight-fold GEMMs --------
// y<64: qkv [4096x1280] from raw q_in (cols 512..768 diverted to VT)
// y==64: fold1 = WTmerge_top @ projbf; y==65: foldx
__global__ __launch_bounds__(256) void gemm_qkv_fold(
    const float* __restrict__ qin, const float* __restrict__ n1g,
    const float* __restrict__ n1b,
    const unsigned short* __restrict__ WT1, unsigned short* __restrict__ A1,
    const unsigned short* __restrict__ WTmerge, const unsigned short* __restrict__ projbf,
    unsigned short* __restrict__ WTf1,
    const unsigned short* __restrict__ WTmergex, const unsigned short* __restrict__ projxbf,
    unsigned short* __restrict__ WTfx,
    unsigned short* __restrict__ VT)
{
    __shared__ unsigned short Alds[64][72];
    __shared__ unsigned short Wlds[64][72];
    if (blockIdx.y >= 64) {
        if (blockIdx.x >= 16) return;
        int row0 = (blockIdx.x >> 2) * 64, col0 = (blockIdx.x & 3) * 64;
        if (blockIdx.y == 64)
            gemm_body<0,0,1,0,0>(WTmerge, 512, nullptr, nullptr, nullptr, projbf,
                nullptr, nullptr, 0, WTf1, 256, 256, row0, col0, Alds, Wlds, nullptr, 0);
        else
            gemm_body<0,0,1,0,0>(WTmergex, 512, nullptr, nullptr, nullptr, projxbf,
                nullptr, nullptr, 0, WTfx, 256, 256, row0, col0, Alds, Wlds, nullptr, 0);
    } else {
        gemm_body<0,0,1,1,1>(nullptr, 0, qin, n1g, n1b, WT1,
            nullptr, nullptr, 0, A1, 1280, 256, blockIdx.y * 64, blockIdx.x * 64,
            Alds, Wlds, VT, 512);
    }
}

// ---------------- dual-A GEMM: LN(out)@[caq|Base_x] + NVB@WT3 (+V->VT) --------------
__global__ __launch_bounds__(256) void gemm64_dual(
    const float* __restrict__ outp, const float* __restrict__ nqg,
    const float* __restrict__ nqb,
    const unsigned short* __restrict__ NVB,
    const unsigned short* __restrict__ WT2,
    const unsigned short* __restrict__ WT3,
    unsigned short* __restrict__ A2,
    unsigned short* __restrict__ A3,
    unsigned short* __restrict__ VT)
{
    __shared__ unsigned short Alds[64][72];
    __shared__ unsigned short Wlds[64][72];
    if (blockIdx.x < 8)
        gemm_body<0,0,1,0,1>(nullptr, 0, outp, nqg, nqb, WT2,
            nullptr, nullptr, 0, A2, 512, 256, blockIdx.y * 64, blockIdx.x * 64,
            Alds, Wlds, nullptr, 0);
    else
        gemm_body<0,0,1,1,0>(NVB, 256, nullptr, nullptr, nullptr, WT3,
            nullptr, nullptr, 0, A3, 768, 256, blockIdx.y * 64, (blockIdx.x - 8) * 64,
            Alds, Wlds, VT, 256);
}

// ---------------- fc1 GEMM with fused LN(out) on A and gelu on output ---------------
__global__ __launch_bounds__(256) void gemm64_ln(
    const float* __restrict__ Af, const float* __restrict__ lng,
    const float* __restrict__ lnb,
    const unsigned short* __restrict__ Wt,
    const float* __restrict__ bias,
    unsigned short* __restrict__ Cp, int ldc)
{
    __shared__ unsigned short Alds[64][72];
    __shared__ unsigned short Wlds[64][72];
    gemm_body<1,0,1,0,1>(nullptr, 0, Af, lng, lnb, Wt, bias, nullptr, 0,
                         Cp, ldc, 256, blockIdx.y * 64, blockIdx.x * 64,
                         Alds, Wlds, nullptr, 0);
}

// ---------------- split-K 8-wave GEMM (fc2) ----------------
template<int ACT, int RESID, int OUTBF>
__global__ __launch_bounds__(512) void gemm64x8(
    const unsigned short* __restrict__ A, int lda,
    const unsigned short* __restrict__ Wt,
    const float* __restrict__ bias,
    const float* __restrict__ resid, int ldr,
    void* __restrict__ Cp, int ldc, int Kc)
{
    __shared__ unsigned short Alds[2][64][72];
    __shared__ unsigned short Wlds[2][64][72];
    __shared__ float Red[64][68];
    const int tid = threadIdx.x;
    const int g = tid >> 8;
    const int t = tid & 255;
    const int wid2 = (tid >> 6) & 3, lane = tid & 63;
    const int lm = lane & 15, quad = lane >> 4;
    const int wr = wid2 >> 1, wc = wid2 & 1;
    const int row0 = blockIdx.y * 64, col0 = blockIdx.x * 64;
    const int ar = t >> 2, ac = (t & 3) * 16;
    const int KH = Kc >> 1;
    const unsigned short* Ag = A  + (size_t)(row0 + ar) * lda + g * KH + ac;
    const unsigned short* Wg = Wt + (size_t)(col0 + ar) * Kc  + g * KH + ac;

    us8 a0 = *(const us8*)Ag;
    us8 a1 = *(const us8*)(Ag + 8);
    us8 w0 = *(const us8*)Wg;
    us8 w1 = *(const us8*)(Wg + 8);

    ffrag acc[2][2];
    #pragma unroll
    for (int mi = 0; mi < 2; ++mi)
        #pragma unroll
        for (int ni = 0; ni < 2; ++ni)
            acc[mi][ni] = (ffrag){0.f, 0.f, 0.f, 0.f};

    for (int k0 = 0;;) {
        __syncthreads();
        *(us8*)&Alds[g][ar][ac]   = a0;
        *(us8*)&Alds[g][ar][ac+8] = a1;
        *(us8*)&Wlds[g][ar][ac]   = w0;
        *(us8*)&Wlds[g][ar][ac+8] = w1;
        __syncthreads();
        k0 += 64;
        if (k0 < KH) {
            a0 = *(const us8*)(Ag + k0);
            a1 = *(const us8*)(Ag + k0 + 8);
            w0 = *(const us8*)(Wg + k0);
            w1 = *(const us8*)(Wg + k0 + 8);
        }
        #pragma unroll
        for (int kc = 0; kc < 2; ++kc) {
            bfrag af[2], bw[2];
            #pragma unroll
            for (int mi = 0; mi < 2; ++mi)
                af[mi] = *(const bfrag*)&Alds[g][wr*32 + mi*16 + lm][kc*32 + quad*8];
            #pragma unroll
            for (int ni = 0; ni < 2; ++ni)
                bw[ni] = *(const bfrag*)&Wlds[g][wc*32 + ni*16 + lm][kc*32 + quad*8];
            #pragma unroll
            for (int mi = 0; mi < 2; ++mi)
                #pragma unroll
                for (int ni = 0; ni < 2; ++ni)
                    acc[mi][ni] = __builtin_amdgcn_mfma_f32_16x16x32_bf16(
                        af[mi], bw[ni], acc[mi][ni], 0, 0, 0);
        }
        if (k0 >= KH) break;
    }
    __syncthreads();
    if (g == 1) {
        #pragma unroll
        for (int mi = 0; mi < 2; ++mi)
            #pragma unroll
            for (int ni = 0; ni < 2; ++ni) {
                int lr = wr*32 + mi*16 + quad*4;
                int lc = wc*32 + ni*16 + lm;
                #pragma unroll
                for (int r = 0; r < 4; ++r)
                    Red[lr + r][lc] = acc[mi][ni][r];
            }
    }
    __syncthreads();
    if (g == 0) {
        #pragma unroll
        for (int mi = 0; mi < 2; ++mi) {
            #pragma unroll
            for (int ni = 0; ni < 2; ++ni) {
                int lr = wr*32 + mi*16 + quad*4;
                int lc = wc*32 + ni*16 + lm;
                int gr = row0 + lr;
                int gc = col0 + lc;
                float bv = bias ? bias[gc] : 0.f;
                #pragma unroll
                for (int r = 0; r < 4; ++r) {
                    float o = acc[mi][ni][r] + Red[lr + r][lc] + bv;
                    if (ACT == 1) o = gelu_exact(o);
                    if (RESID) o += resid[(size_t)(gr + r) * ldr + gc];
                    if (OUTBF) ((unsigned short*)Cp)[(size_t)(gr + r) * ldc + gc] = f2bf(o);
                    else       ((float*)Cp)[(size_t)(gr + r) * ldc + gc] = o;
                }
            }
        }
    }
}

// ---------------- dual-source split-K: O@WTfold + knn@WTmerge_knn ----------------
__global__ __launch_bounds__(512) void gemm64x8f(
    const unsigned short* __restrict__ O,
    const unsigned short* __restrict__ Akn,
    const unsigned short* __restrict__ W0,
    const unsigned short* __restrict__ W1,
    const float* __restrict__ bias,
    const float* __restrict__ resid,
    float* __restrict__ Cp)
{
    __shared__ unsigned short Alds[2][64][72];
    __shared__ unsigned short Wlds[2][64][72];
    __shared__ float Red[64][68];
    const int tid = threadIdx.x;
    const int g = tid >> 8;
    const int t = tid & 255;
    const int wid2 = (tid >> 6) & 3, lane = tid & 63;
    const int lm = lane & 15, quad = lane >> 4;
    const int wr = wid2 >> 1, wc = wid2 & 1;
    const int row0 = blockIdx.y * 64, col0 = blockIdx.x * 64;
    const int ar = t >> 2, ac = (t & 3) * 16;
    const int grow = row0 + ar;

    const unsigned short* Ag = g ? Akn + (size_t)grow * 512 + ac
                                 : O   + (size_t)grow * 256 + ac;
    const unsigned short* Wg = g ? W1 + (size_t)(col0 + ar) * 512 + ac
                                 : W0 + (size_t)(col0 + ar) * 256 + ac;

    us8 a0 = *(const us8*)Ag;
    us8 a1 = *(const us8*)(Ag + 8);
    us8 w0 = *(const us8*)Wg;
    us8 w1 = *(const us8*)(Wg + 8);

    ffrag acc[2][2];
    #pragma unroll
    for (int mi = 0; mi < 2; ++mi)
        #pragma unroll
        for (int ni = 0; ni < 2; ++ni)
            acc[mi][ni] = (ffrag){0.f, 0.f, 0.f, 0.f};

    for (int k0 = 0;;) {
        __syncthreads();
        *(us8*)&Alds[g][ar][ac]   = a0;
        *(us8*)&Alds[g][ar][ac+8] = a1;
        *(us8*)&Wlds[g][ar][ac]   = w0;
        *(us8*)&Wlds[g][ar][ac+8] = w1;
        __syncthreads();
        k0 += 64;
        if (k0 < 256) {
            a0 = *(const us8*)(Ag + k0);
            a1 = *(const us8*)(Ag + k0 + 8);
            w0 = *(const us8*)(Wg + k0);
            w1 = *(const us8*)(Wg + k0 + 8);
        }
        #pragma unroll
        for (int kc = 0; kc < 2; ++kc) {
            bfrag af[2], bw[2];
            #pragma unroll
            for (int mi = 0; mi < 2; ++mi)
                af[mi] = *(const bfrag*)&Alds[g][wr*32 + mi*16 + lm][kc*32 + quad*8];
            #pragma unroll
            for (int ni = 0; ni < 2; ++ni)
                bw[ni] = *(const bfrag*)&Wlds[g][wc*32 + ni*16 + lm][kc*32 + quad*8];
            #pragma unroll
            for (int mi = 0; mi < 2; ++mi)
                #pragma unroll
                for (int ni = 0; ni < 2; ++ni)
                    acc[mi][ni] = __builtin_amdgcn_mfma_f32_16x16x32_bf16(
                        af[mi], bw[ni], acc[mi][ni], 0, 0, 0);
        }
        if (k0 >= 256) break;
    }
    __syncthreads();
    if (g == 1) {
        #pragma unroll
        for (int mi = 0; mi < 2; ++mi)
            #pragma unroll
            for (int ni = 0; ni < 2; ++ni) {
                int lr = wr*32 + mi*16 + quad*4;
                int lc = wc*32 + ni*16 + lm;
                #pragma unroll
                for (int r = 0; r < 4; ++r)
                    Red[lr + r][lc] = acc[mi][ni][r];
            }
    }
    __syncthreads();
    if (g == 0) {
        #pragma unroll
        for (int mi = 0; mi < 2; ++mi) {
            #pragma unroll
            for (int ni = 0; ni < 2; ++ni) {
                int lr = wr*32 + mi*16 + quad*4;
                int lc = wc*32 + ni*16 + lm;
                int gr = row0 + lr;
                int gc = col0 + lc;
                float bv = bias[gc];
                #pragma unroll
                for (int r = 0; r < 4; ++r)
                    Cp[(size_t)(gr + r) * 256 + gc] =
                        acc[mi][ni][r] + Red[lr + r][lc] + bv
                        + resid[(size_t)(gr + r) * 256 + gc];
            }
        }
    }
}

// ---------------- packed: flash attention (z==0) + KNN gather (z>=1) ----------------
__global__ __launch_bounds__(256) void attn_gather(
    const unsigned short* __restrict__ Qp, int ldq,
    const unsigned short* __restrict__ Kp, int ldk,
    const unsigned short* __restrict__ VT,
    unsigned short* __restrict__ Op,
    const unsigned short* __restrict__ P, int ldp,
    const unsigned short* __restrict__ Base, int ldb,
    const float* __restrict__ gbias, const int* __restrict__ idx,
    unsigned short* __restrict__ gout, int ldgo)
{
    __shared__ unsigned short Klds[64][40];
    __shared__ __align__(16) unsigned short Vt[32][72];
    __shared__ __align__(16) unsigned short Plds[4][16][72];
    int tid = threadIdx.x, wid = tid >> 6, lane = tid & 63;

    if (blockIdx.z >= 1) {
        // ---- gather branch ----
        int gbid = blockIdx.x + 64 * (blockIdx.y + 8 * (blockIdx.z - 1));
        int q = gbid * 4 + wid;
        int b = q >> 11;
        int c = lane * 4;
        ushort4 bu = *(const ushort4*)(Base + (size_t)q * ldb + c);
        float4 bi = *(const float4*)(gbias + c);
        float bsx = bf2f(bu.x) + bi.x, bsy = bf2f(bu.y) + bi.y;
        float bsz = bf2f(bu.z) + bi.z, bsw = bf2f(bu.w) + bi.w;
        float4 acc = make_float4(-3e38f, -3e38f, -3e38f, -3e38f);
        const int* ip = idx + (size_t)q * 8;
        #pragma unroll
        for (int k = 0; k < 8; ++k) {
            int j = ip[k];
            ushort4 pu = *(const ushort4*)(P + ((size_t)(b * NKVC + j)) * ldp + c);
            float t;
            t = bsx + bf2f(pu.x); t = t > 0.f ? t : 0.2f * t; acc.x = fmaxf(acc.x, t);
            t = bsy + bf2f(pu.y); t = t > 0.f ? t : 0.2f * t; acc.y = fmaxf(acc.y, t);
            t = bsz + bf2f(pu.z); t = t > 0.f ? t : 0.2f * t; acc.z = fmaxf(acc.z, t);
            t = bsw + bf2f(pu.w); t = t > 0.f ? t : 0.2f * t; acc.w = fmaxf(acc.w, t);
        }
        ushort4 o;
        o.x = f2bf(acc.x); o.y = f2bf(acc.y); o.z = f2bf(acc.z); o.w = f2bf(acc.w);
        *(ushort4*)(gout + (size_t)q * ldgo + c) = o;
        return;
    }

    // ---- attention branch ----
    int bb = blockIdx.x >> 5, qc = blockIdx.x & 31;
    int h = blockIdx.y;
    int hoff = h * 32;
    int lm = lane & 15, quad = lane >> 4;
    size_t qbase  = (size_t)bb * NQC;
    size_t kvbase = (size_t)bb * NKVC;
    int q0 = qc * 64 + wid * 16;

    bfrag aq = *(const bfrag*)(Qp + (qbase + q0 + lm) * (size_t)ldq + hoff + quad * 8);

    float l_r[4] = {0.f, 0.f, 0.f, 0.f};
    ffrag oacc[2];
    oacc[0] = (ffrag){0.f, 0.f, 0.f, 0.f};
    oacc[1] = (ffrag){0.f, 0.f, 0.f, 0.f};

    const int kkey = tid >> 2, kd0 = (tid & 3) * 8;
    const int vrow = tid >> 3, vp0 = (tid & 7) * 8;
    const unsigned short* kg0 = Kp + (kvbase + kkey) * (size_t)ldk + hoff + kd0;
    const unsigned short* vg0 = VT + (((size_t)bb * 8 + h) * 32 + vrow) * 2048 + vp0;

    for (int kt = 0; kt < 32; ++kt) {
        us8 kv = *(const us8*)(kg0 + (size_t)kt * 64 * ldk);
        us8 vv = *(const us8*)(vg0 + kt * 64);
        __syncthreads();
        *(us8*)&Klds[kkey][kd0] = kv;
        *(us8*)&Vt[vrow][vp0]   = vv;
        __syncthreads();

        ffrag sacc[4];
        #pragma unroll
        for (int t = 0; t < 4; ++t) {
            bfrag bk = *(const bfrag*)&Klds[t*16 + lm][quad * 8];
            sacc[t] = __builtin_amdgcn_mfma_f32_16x16x32_bf16(
                aq, bk, (ffrag){0.f,0.f,0.f,0.f}, 0, 0, 0);
        }

        #pragma unroll
        for (int r = 0; r < 4; ++r) {
            float p0 = fexp2(sacc[0][r]), p1 = fexp2(sacc[1][r]);
            float p2 = fexp2(sacc[2][r]), p3 = fexp2(sacc[3][r]);
            l_r[r] += (p0 + p1) + (p2 + p3);
            *(uint2*)&Plds[wid][quad*4 + r][lm << 2] =
                make_uint2(cvt_pk_bf16(p0, p1), cvt_pk_bf16(p2, p3));
        }
        asm volatile("s_waitcnt lgkmcnt(0)" ::: "memory");  // wave-private P RAW

        #pragma unroll
        for (int kc = 0; kc < 2; ++kc) {
            bfrag ap  = *(const bfrag*)&Plds[wid][lm][kc*32 + quad*8];
            bfrag bv0 = *(const bfrag*)&Vt[lm][kc*32 + quad*8];
            bfrag bv1 = *(const bfrag*)&Vt[16 + lm][kc*32 + quad*8];
            oacc[0] = __builtin_amdgcn_mfma_f32_16x16x32_bf16(ap, bv0, oacc[0], 0, 0, 0);
            oacc[1] = __builtin_amdgcn_mfma_f32_16x16x32_bf16(ap, bv1, oacc[1], 0, 0, 0);
        }
    }
    #pragma unroll
    for (int r = 0; r < 4; ++r) {
        float a = l_r[r];
        a += __shfl_xor(a, 1); a += __shfl_xor(a, 2);
        a += __shfl_xor(a, 4); a += __shfl_xor(a, 8);
        l_r[r] = 1.0f / a;
    }
    #pragma unroll
    for (int nt = 0; nt < 2; ++nt)
        #pragma unroll
        for (int r = 0; r < 4; ++r)
            Op[(qbase + q0 + quad*4 + r) * 256 + hoff + nt*16 + lm]
                = f2bf(oacc[nt][r] * l_r[r]);
}

extern "C" void kernel_launch(void* const* d_in, const int* in_sizes, int n_in,
                              void* d_out, int out_size, void* d_ws, size_t ws_size,
                              hipStream_t stream) {
    const float* q_in   = (const float*)d_in[0];
    const float* v_in   = (const float*)d_in[1];
    const int*   idx_s  = (const int*)d_in[4];
    const int*   idx_x  = (const int*)d_in[5];
    const float* n1g = (const float*)d_in[6],  *n1b = (const float*)d_in[7];
    const float* nqg = (const float*)d_in[8],  *nqb = (const float*)d_in[9];
    const float* nvg = (const float*)d_in[10], *nvb = (const float*)d_in[11];
    const float* n2g = (const float*)d_in[12], *n2b = (const float*)d_in[13];
    const float* sa_qkv_w  = (const float*)d_in[14];
    const float* sa_proj_w = (const float*)d_in[15];
    const float* sa_proj_b = (const float*)d_in[16];
    const float* ca_q_w    = (const float*)d_in[17];
    const float* ca_kv_w   = (const float*)d_in[18];
    const float* ca_proj_w = (const float*)d_in[19];
    const float* ca_proj_b = (const float*)d_in[20];
    const float* fc1_w = (const float*)d_in[21], *fc1_b = (const float*)d_in[22];
    const float* fc2_w = (const float*)d_in[23], *fc2_b = (const float*)d_in[24];
    const float* knn_w   = (const float*)d_in[25], *knn_b   = (const float*)d_in[26];
    const float* merge_w = (const float*)d_in[27], *merge_b = (const float*)d_in[28];
    const float* knnx_w  = (const float*)d_in[29], *knnx_b  = (const float*)d_in[30];
    const float* mergex_w = (const float*)d_in[31], *mergex_b = (const float*)d_in[32];
    float* out = (float*)d_out;

    unsigned short* A1      = (unsigned short*)d_ws;           // 4096x1280 bf16
    unsigned short* A2      = A1;                              // 4096x512 (stage2 overlay)
    unsigned short* A3      = A1 + (size_t)4096 * 512;         // 4096x768 (stage2 overlay)
    unsigned short* Hb      = A1;                              // 4096x1024 (stage3 overlay)
    unsigned short* KN      = A1 + (size_t)4096 * 1280;        // 4096x256 knn_out (CC+256 view)
    unsigned short* CC      = KN;                              // 4096x512 [unused | knn_out]
    unsigned short* XB      = CC + (size_t)4096 * 512;         // (dead slot, kept for layout)
    unsigned short* NVB     = XB + (size_t)4096 * 256;         // 4096x256 LN(v)
    unsigned short* WT      = NVB + (size_t)4096 * 256;        // weights, 1572864 us
    unsigned short* WT1     = WT;
    unsigned short* projbf  = WT + 327680;                     // proj bf16 [k][n] linear
    unsigned short* WTmerge = WT + 393216;
    unsigned short* WT2     = WT + 524288;
    unsigned short* WT3     = WT + 655360;
    unsigned short* projxbf = WT + 851968;                     // projx bf16 [k][n] linear
    unsigned short* WTmergex= WT + 917504;
    unsigned short* WTfc1   = WT + 1048576;
    unsigned short* WTfc2   = WT + 1310720;
    unsigned short* Opart   = WT + 1572864;                    // [4096][256] bf16 (normalized O)
    unsigned short* WTf1    = Opart + (size_t)4096 * 256;      // [256][256] folded
    unsigned short* WTfx    = WTf1 + 65536;                    // [256][256] folded
    float* bf1 = (float*)(WTfx + 65536);                       // folded bias stage1 [256]
    float* bfx = bf1 + 256;                                    // folded bias stage2 [256]
    unsigned short* VT = (unsigned short*)(bfx + 256);         // [2][8][32][2048] bf16

    dim3 blk(256), blk8(512);
    dim3 gAG(64, 8, 3);     // z==0: attn (512 blocks); z in {1,2}: gather (1024 blocks)

    // prep: tiled-transpose weights + linear copies + LN(v) + bias folds
    prep_w<<<dim3(1506), blk, 0, stream>>>(sa_qkv_w, knn_w, sa_proj_w, merge_w,
        ca_q_w, knnx_w, ca_kv_w, ca_proj_w, mergex_w, fc1_w, fc2_w, WT,
        v_in, nvg, nvb, NVB,
        sa_proj_b, merge_b, bf1,
        ca_proj_b, mergex_b, bfx);

    // ---- stage 1 ----
    gemm_qkv_fold<<<dim3(20,66), blk, 0, stream>>>(q_in, n1g, n1b, WT1, A1,
        WTmerge, projbf, WTf1, WTmergex, projxbf, WTfx, VT);                        // LN(q)@W1 + V->VT + folds
    attn_gather<<<gAG, blk, 0, stream>>>(A1, 1280, A1+256, 1280, VT,
        Opart, A1+768, 1280, A1+1024, 1280, knn_b, idx_s, CC+256, 512);
    gemm64x8f<<<dim3(4,64), blk8, 0, stream>>>(Opart, CC+256,
        WTf1, WTmerge+256, bf1, q_in, out);                                         // q = q + merge(fused)

    // ---- stage 2 ----
    gemm64_dual<<<dim3(20,64), blk, 0, stream>>>(out, nqg, nqb, NVB,
        WT2, WT3, A2, A3, VT);                                                      // LN fused + V->VT
    attn_gather<<<gAG, blk, 0, stream>>>(A2, 512, A3, 768, VT,
        Opart, A3+512, 768, A2+256, 512, knnx_b, idx_x, CC+256, 512);
    gemm64x8f<<<dim3(4,64), blk8, 0, stream>>>(Opart, CC+256,
        WTfx, WTmergex+256, bfx, out, out);                                         // q = q + mergex(fused)

    // ---- stage 3 ----
    gemm64_ln<<<dim3(16,64), blk, 0, stream>>>(out, n2g, n2b, WTfc1,
        fc1_b, Hb, 1024);                                                           // gelu(LN(q)@fc1+b), LN fused
    gemm64x8<0,1,0><<<dim3(4,64), blk8, 0, stream>>>(Hb, 1024, WTfc2,
        fc2_b, out, 256, out, 256, 1024);                                           // q += fc2
}

// Round 7
// 236.857 us; speedup vs baseline: 1.2134x; 1.2134x over previous
//
#include <hip/hip_runtime.h>
#include <math.h>

#define NQC   2048
#define NKVC  2048
#define DIMC  256
// 1/sqrt(32) * log2(e): attention scale with exp->exp2 base change folded in
#define SCALEF 0.2550348810731232f

typedef short bfrag __attribute__((ext_vector_type(8)));   // 8 bf16 = 4 VGPRs
typedef float ffrag __attribute__((ext_vector_type(4)));   // MFMA C/D
typedef unsigned short us8 __attribute__((ext_vector_type(8)));

__device__ __forceinline__ float gelu_exact(float x) {
    return 0.5f * x * (1.0f + erff(x * 0.70710678118654752f));
}
__device__ __forceinline__ unsigned short f2bf(float f) {
    union { float f; unsigned u; } v; v.f = f;
    unsigned r = v.u + 0x7FFFu + ((v.u >> 16) & 1u);   // RNE
    return (unsigned short)(r >> 16);
}
__device__ __forceinline__ float bf2f(unsigned short u) {
    union { unsigned u; float f; } v; v.u = ((unsigned)u) << 16;
    return v.f;
}
__device__ __forceinline__ float fexp2(float x) {
    float r; asm("v_exp_f32 %0, %1" : "=v"(r) : "v"(x)); return r;
}
__device__ __forceinline__ unsigned cvt_pk_bf16(float lo, float hi) {
    unsigned r; asm("v_cvt_pk_bf16_f32 %0, %1, %2" : "=v"(r) : "v"(lo), "v"(hi));
    return r;
}

// ---------------- LN device body (one wave per row) ----------------
__device__ __forceinline__ void ln_row(
    const float* __restrict__ x, const float* __restrict__ g,
    const float* __restrict__ b, unsigned short* __restrict__ y, int row)
{
    int lane = threadIdx.x & 63;
    const float* xr = x + (size_t)row * DIMC + lane * 4;
    float4 vv = *(const float4*)xr;
    float s  = vv.x + vv.y + vv.z + vv.w;
    float sq = vv.x*vv.x + vv.y*vv.y + vv.z*vv.z + vv.w*vv.w;
    #pragma unroll
    for (int off = 32; off >= 1; off >>= 1) {
        s  += __shfl_xor(s, off);
        sq += __shfl_xor(sq, off);
    }
    float mean = s * (1.0f/DIMC);
    float inv  = rsqrtf(sq * (1.0f/DIMC) - mean*mean + 1e-5f);
    float4 gg = *(const float4*)(g + lane*4);
    float4 bb = *(const float4*)(b + lane*4);
    ushort4 o;
    o.x = f2bf((vv.x - mean) * inv * gg.x + bb.x);
    o.y = f2bf((vv.y - mean) * inv * gg.y + bb.y);
    o.z = f2bf((vv.z - mean) * inv * gg.z + bb.z);
    o.w = f2bf((vv.w - mean) * inv * gg.w + bb.w);
    *(ushort4*)(y + (size_t)row * DIMC + lane * 4) = o;
}

// ---------------- packed prep: tiled-transpose weights + copies + LN(q) + LN(v) + folds
// blocks 0..351:    64x64 weight tiles, coalesced load -> LDS transpose -> coalesced store
// blocks 352..479:  linear bf16 copies (projbf, projxbf)
// blocks 480..1503: LN(q) -> XB
// blocks 1504..2527:LN(v) -> NVB
// blocks 2528..2529:folded biases
__global__ __launch_bounds__(256) void prep_w(
    const float* __restrict__ qkv, const float* __restrict__ knn,
    const float* __restrict__ proj, const float* __restrict__ merge,
    const float* __restrict__ caq, const float* __restrict__ knnx,
    const float* __restrict__ cakv, const float* __restrict__ projx,
    const float* __restrict__ mergex, const float* __restrict__ fc1,
    const float* __restrict__ fc2, unsigned short* __restrict__ dst,
    const float* __restrict__ lx, const float* __restrict__ lg,
    const float* __restrict__ lb, unsigned short* __restrict__ ly,
    const float* __restrict__ vx, const float* __restrict__ vg,
    const float* __restrict__ vb, unsigned short* __restrict__ vy,
    const float* __restrict__ pb1, const float* __restrict__ mb1, float* __restrict__ bf1o,
    const float* __restrict__ pbx, const float* __restrict__ mbx, float* __restrict__ bfxo)
{
    __shared__ unsigned short T[64][72];
    int blk = blockIdx.x, tid = threadIdx.x;
    if (blk >= 2528) {
        // folded bias: bfold[m] = merge_b[m] + sum_k proj_b[k] * merge_w[k][m]
        const float* bp = (blk == 2528) ? pb1 : pbx;
        const float* Wm = (blk == 2528) ? merge : mergex;
        const float* bm = (blk == 2528) ? mb1 : mbx;
        float* o        = (blk == 2528) ? bf1o : bfxo;
        int m = tid;
        float acc = bm[m];
        for (int k = 0; k < 256; ++k) acc += bp[k] * Wm[(size_t)k * 256 + m];
        o[m] = acc;
        return;
    }
    if (blk >= 1504) {   // LN(v)
        ln_row(vx, vg, vb, vy, (blk - 1504) * 4 + (tid >> 6));
        return;
    }
    if (blk >= 480) {    // LN(q)
        ln_row(lx, lg, lb, ly, (blk - 480) * 4 + (tid >> 6));
        return;
    }
    if (blk >= 352) {    // linear copies (already [k][n]-major in both layouts)
        int l = blk - 352;
        const float* s; unsigned short* d;
        if (l < 64) { s = proj;  d = dst + 327680; }
        else        { s = projx; d = dst + 851968; l -= 64; }
        int e = (l * 256 + tid) * 4;
        float4 v = *(const float4*)(s + e);
        ushort4 o;
        o.x = f2bf(v.x); o.y = f2bf(v.y); o.z = f2bf(v.z); o.w = f2bf(v.w);
        *(ushort4*)(d + e) = o;
        return;
    }
    // ---- 64x64 transpose tile: dst[n][k] <- src[k][n] (optionally minus src2, scaled)
    int t = blk;
    const float* src; const float* src2 = nullptr; int sN;
    unsigned short* dp; int dK; float scale = 1.0f; int n0, k0;
    if (t < 48)       { src = qkv;          sN = 768;  dp = dst;           dK = 256;
                        n0 = (t % 12) * 64; k0 = (t / 12) * 64; if (n0 < 256) scale = SCALEF; }
    else if (t < 64)  { int u = t - 48;  src = knn;          sN = 256; dp = dst + 196608; dK = 256;
                        n0 = (u & 3) * 64; k0 = (u >> 2) * 64; }             // knn lo -> WT1 rows 768..1024
    else if (t < 80)  { int u = t - 64;  src = knn + 65536;  src2 = knn; sN = 256; dp = dst + 262144; dK = 256;
                        n0 = (u & 3) * 64; k0 = (u >> 2) * 64; }             // knn hi-lo -> rows 1024..1280
    else if (t < 112) { int u = t - 80;  src = merge;        sN = 256; dp = dst + 393216; dK = 512;
                        n0 = (u & 3) * 64; k0 = (u >> 2) * 64; }
    else if (t < 128) { int u = t - 112; src = caq;          sN = 256; dp = dst + 524288; dK = 256;
                        n0 = (u & 3) * 64; k0 = (u >> 2) * 64; scale = SCALEF; }
    else if (t < 144) { int u = t - 128; src = knnx + 65536; src2 = knnx; sN = 256; dp = dst + 589824; dK = 256;
                        n0 = (u & 3) * 64; k0 = (u >> 2) * 64; }             // WT2 rows 256..512
    else if (t < 176) { int u = t - 144; src = cakv;         sN = 512; dp = dst + 655360; dK = 256;
                        n0 = (u & 7) * 64; k0 = (u >> 3) * 64; }
    else if (t < 192) { int u = t - 176; src = knnx;         sN = 256; dp = dst + 786432; dK = 256;
                        n0 = (u & 3) * 64; k0 = (u >> 2) * 64; }             // WT3 rows 512..768
    else if (t < 224) { int u = t - 192; src = mergex;       sN = 256; dp = dst + 917504; dK = 512;
                        n0 = (u & 3) * 64; k0 = (u >> 2) * 64; }
    else if (t < 288) { int u = t - 224; src = fc1;          sN = 1024; dp = dst + 1048576; dK = 256;
                        n0 = (u & 15) * 64; k0 = (u >> 4) * 64; }
    else              { int u = t - 288; src = fc2;          sN = 256; dp = dst + 1310720; dK = 1024;
                        n0 = (u & 3) * 64; k0 = (u >> 2) * 64; }
    int r = tid >> 2, c0 = (tid & 3) * 16;
    float va[16];
    {
        const float* sp = src + (size_t)(k0 + r) * sN + n0 + c0;
        float4 f0 = *(const float4*)(sp);
        float4 f1 = *(const float4*)(sp + 4);
        float4 f2 = *(const float4*)(sp + 8);
        float4 f3 = *(const float4*)(sp + 12);
        va[0]=f0.x; va[1]=f0.y; va[2]=f0.z;  va[3]=f0.w;
        va[4]=f1.x; va[5]=f1.y; va[6]=f1.z;  va[7]=f1.w;
        va[8]=f2.x; va[9]=f2.y; va[10]=f2.z; va[11]=f2.w;
        va[12]=f3.x; va[13]=f3.y; va[14]=f3.z; va[15]=f3.w;
        if (src2) {
            const float* s2 = src2 + (size_t)(k0 + r) * sN + n0 + c0;
            float4 h0 = *(const float4*)(s2);
            float4 h1 = *(const float4*)(s2 + 4);
            float4 h2 = *(const float4*)(s2 + 8);
            float4 h3 = *(const float4*)(s2 + 12);
            va[0]-=h0.x; va[1]-=h0.y; va[2]-=h0.z;  va[3]-=h0.w;
            va[4]-=h1.x; va[5]-=h1.y; va[6]-=h1.z;  va[7]-=h1.w;
            va[8]-=h2.x; va[9]-=h2.y; va[10]-=h2.z; va[11]-=h2.w;
            va[12]-=h3.x; va[13]-=h3.y; va[14]-=h3.z; va[15]-=h3.w;
        }
    }
    #pragma unroll
    for (int i = 0; i < 16; ++i) T[c0 + i][r] = f2bf(va[i] * scale);
    __syncthreads();
    {
        int n = tid >> 2, kk = (tid & 3) * 16;
        unsigned short* d = dp + (size_t)(n0 + n) * dK + k0 + kk;
        *(us8*)d       = *(const us8*)&T[n][kk];
        *(us8*)(d + 8) = *(const us8*)&T[n][kk + 8];
    }
}

// ---------------- single-source LayerNorm ----------------
__global__ __launch_bounds__(256) void ln_b(
    const float* __restrict__ x, const float* __restrict__ g,
    const float* __restrict__ b, unsigned short* __restrict__ y)
{
    ln_row(x, g, b, y, blockIdx.x * 4 + (threadIdx.x >> 6));
}

// ---------------- bf16 MFMA GEMM body, 64x64 tile, BK=64 ----------------
template<int ACT, int RESID, int OUTBF>
__device__ __forceinline__ void gemm_body(
    const unsigned short* __restrict__ A, int lda,
    const unsigned short* __restrict__ Wt,
    const float* __restrict__ bias,
    const float* __restrict__ resid, int ldr,
    void* __restrict__ Cp, int ldc, int Kc, int row0, int col0,
    unsigned short (* __restrict__ Alds)[72],
    unsigned short (* __restrict__ Wlds)[72])
{
    const int tid = threadIdx.x;
    const int wid = tid >> 6, lane = tid & 63;
    const int lm = lane & 15, quad = lane >> 4;
    const int wr = wid >> 1, wc = wid & 1;
    const int ar = tid >> 2, ac = (tid & 3) * 16;
    const unsigned short* Ag = A  + (size_t)(row0 + ar) * lda + ac;
    const unsigned short* Wg = Wt + (size_t)(col0 + ar) * Kc  + ac;

    us8 a0 = *(const us8*)Ag;
    us8 a1 = *(const us8*)(Ag + 8);
    us8 w0 = *(const us8*)Wg;
    us8 w1 = *(const us8*)(Wg + 8);

    ffrag acc[2][2];
    #pragma unroll
    for (int mi = 0; mi < 2; ++mi)
        #pragma unroll
        for (int ni = 0; ni < 2; ++ni)
            acc[mi][ni] = (ffrag){0.f, 0.f, 0.f, 0.f};

    for (int k0 = 0;;) {
        __syncthreads();
        *(us8*)&Alds[ar][ac]   = a0;
        *(us8*)&Alds[ar][ac+8] = a1;
        *(us8*)&Wlds[ar][ac]   = w0;
        *(us8*)&Wlds[ar][ac+8] = w1;
        __syncthreads();
        k0 += 64;
        if (k0 < Kc) {
            a0 = *(const us8*)(Ag + k0);
            a1 = *(const us8*)(Ag + k0 + 8);
            w0 = *(const us8*)(Wg + k0);
            w1 = *(const us8*)(Wg + k0 + 8);
        }
        #pragma unroll
        for (int kc = 0; kc < 2; ++kc) {
            bfrag af[2], bw[2];
            #pragma unroll
            for (int mi = 0; mi < 2; ++mi)
                af[mi] = *(const bfrag*)&Alds[wr*32 + mi*16 + lm][kc*32 + quad*8];
            #pragma unroll
            for (int ni = 0; ni < 2; ++ni)
                bw[ni] = *(const bfrag*)&Wlds[wc*32 + ni*16 + lm][kc*32 + quad*8];
            #pragma unroll
            for (int mi = 0; mi < 2; ++mi)
                #pragma unroll
                for (int ni = 0; ni < 2; ++ni)
                    acc[mi][ni] = __builtin_amdgcn_mfma_f32_16x16x32_bf16(
                        af[mi], bw[ni], acc[mi][ni], 0, 0, 0);
        }
        if (k0 >= Kc) break;
    }
    #pragma unroll
    for (int mi = 0; mi < 2; ++mi) {
        #pragma unroll
        for (int ni = 0; ni < 2; ++ni) {
            int gr = row0 + wr*32 + mi*16 + quad*4;
            int gc = col0 + wc*32 + ni*16 + lm;
            float bv = bias ? bias[gc] : 0.f;
            #pragma unroll
            for (int r = 0; r < 4; ++r) {
                float o = acc[mi][ni][r] + bv;
                if (ACT == 1) o = gelu_exact(o);
                if (RESID) o += resid[(size_t)(gr + r) * ldr + gc];
                if (OUTBF) ((unsigned short*)Cp)[(size_t)(gr + r) * ldc + gc] = f2bf(o);
                else       ((float*)Cp)[(size_t)(gr + r) * ldc + gc] = o;
            }
        }
    }
}

template<int ACT, int RESID, int OUTBF>
__global__ __launch_bounds__(256) void gemm64(
    const unsigned short* __restrict__ A, int lda,
    const unsigned short* __restrict__ Wt,
    const float* __restrict__ bias,
    const float* __restrict__ resid, int ldr,
    void* __restrict__ Cp, int ldc, int Kc)
{
    __shared__ unsigned short Alds[64][72];
    __shared__ unsigned short Wlds[64][72];
    gemm_body<ACT,RESID,OUTBF>(A, lda, Wt, bias, resid, ldr, Cp, ldc, Kc,
                               blockIdx.y * 64, blockIdx.x * 64, Alds, Wlds);
}

// ---------------- qkv GEMM + packed weight-fold GEMMs (WTfold = Wproj @ Wm_top) ----------
// y<64: qkv [4096x1280]; y==64: fold1 (16 blocks); y==65: foldx (16 blocks)
__global__ __launch_bounds__(256) void gemm_qkv_fold(
    const unsigned short* __restrict__ XB, const unsigned short* __restrict__ WT1,
    unsigned short* __restrict__ A1,
    const unsigned short* __restrict__ WTmerge, const unsigned short* __restrict__ projbf,
    unsigned short* __restrict__ WTf1,
    const unsigned short* __restrict__ WTmergex, const unsigned short* __restrict__ projxbf,
    unsigned short* __restrict__ WTfx)
{
    __shared__ unsigned short Alds[64][72];
    __shared__ unsigned short Wlds[64][72];
    const unsigned short *A, *Wt; unsigned short* C;
    int lda, ldc, row0, col0;
    if (blockIdx.y >= 64) {
        if (blockIdx.x >= 16) return;
        row0 = (blockIdx.x >> 2) * 64; col0 = (blockIdx.x & 3) * 64;
        lda = 512; ldc = 256;
        if (blockIdx.y == 64) { A = WTmerge;  Wt = projbf;  C = WTf1; }
        else                  { A = WTmergex; Wt = projxbf; C = WTfx; }
    } else {
        A = XB; Wt = WT1; C = A1; lda = 256; ldc = 1280;
        row0 = blockIdx.y * 64; col0 = blockIdx.x * 64;
    }
    gemm_body<0,0,1>(A, lda, Wt, nullptr, nullptr, 0, C, ldc, 256, row0, col0, Alds, Wlds);
}

// ---------------- split-K 8-wave GEMM (fc2) ----------------
template<int ACT, int RESID, int OUTBF>
__global__ __launch_bounds__(512) void gemm64x8(
    const unsigned short* __restrict__ A, int lda,
    const unsigned short* __restrict__ Wt,
    const float* __restrict__ bias,
    const float* __restrict__ resid, int ldr,
    void* __restrict__ Cp, int ldc, int Kc)
{
    __shared__ unsigned short Alds[2][64][72];
    __shared__ unsigned short Wlds[2][64][72];
    __shared__ float Red[64][68];
    const int tid = threadIdx.x;
    const int g = tid >> 8;
    const int t = tid & 255;
    const int wid2 = (tid >> 6) & 3, lane = tid & 63;
    const int lm = lane & 15, quad = lane >> 4;
    const int wr = wid2 >> 1, wc = wid2 & 1;
    const int row0 = blockIdx.y * 64, col0 = blockIdx.x * 64;
    const int ar = t >> 2, ac = (t & 3) * 16;
    const int KH = Kc >> 1;
    const unsigned short* Ag = A  + (size_t)(row0 + ar) * lda + g * KH + ac;
    const unsigned short* Wg = Wt + (size_t)(col0 + ar) * Kc  + g * KH + ac;

    us8 a0 = *(const us8*)Ag;
    us8 a1 = *(const us8*)(Ag + 8);
    us8 w0 = *(const us8*)Wg;
    us8 w1 = *(const us8*)(Wg + 8);

    ffrag acc[2][2];
    #pragma unroll
    for (int mi = 0; mi < 2; ++mi)
        #pragma unroll
        for (int ni = 0; ni < 2; ++ni)
            acc[mi][ni] = (ffrag){0.f, 0.f, 0.f, 0.f};

    for (int k0 = 0;;) {
        __syncthreads();
        *(us8*)&Alds[g][ar][ac]   = a0;
        *(us8*)&Alds[g][ar][ac+8] = a1;
        *(us8*)&Wlds[g][ar][ac]   = w0;
        *(us8*)&Wlds[g][ar][ac+8] = w1;
        __syncthreads();
        k0 += 64;
        if (k0 < KH) {
            a0 = *(const us8*)(Ag + k0);
            a1 = *(const us8*)(Ag + k0 + 8);
            w0 = *(const us8*)(Wg + k0);
            w1 = *(const us8*)(Wg + k0 + 8);
        }
        #pragma unroll
        for (int kc = 0; kc < 2; ++kc) {
            bfrag af[2], bw[2];
            #pragma unroll
            for (int mi = 0; mi < 2; ++mi)
                af[mi] = *(const bfrag*)&Alds[g][wr*32 + mi*16 + lm][kc*32 + quad*8];
            #pragma unroll
            for (int ni = 0; ni < 2; ++ni)
                bw[ni] = *(const bfrag*)&Wlds[g][wc*32 + ni*16 + lm][kc*32 + quad*8];
            #pragma unroll
            for (int mi = 0; mi < 2; ++mi)
                #pragma unroll
                for (int ni = 0; ni < 2; ++ni)
                    acc[mi][ni] = __builtin_amdgcn_mfma_f32_16x16x32_bf16(
                        af[mi], bw[ni], acc[mi][ni], 0, 0, 0);
        }
        if (k0 >= KH) break;
    }
    __syncthreads();
    if (g == 1) {
        #pragma unroll
        for (int mi = 0; mi < 2; ++mi)
            #pragma unroll
            for (int ni = 0; ni < 2; ++ni) {
                int lr = wr*32 + mi*16 + quad*4;
                int lc = wc*32 + ni*16 + lm;
                #pragma unroll
                for (int r = 0; r < 4; ++r)
                    Red[lr + r][lc] = acc[mi][ni][r];
            }
    }
    __syncthreads();
    if (g == 0) {
        #pragma unroll
        for (int mi = 0; mi < 2; ++mi) {
            #pragma unroll
            for (int ni = 0; ni < 2; ++ni) {
                int lr = wr*32 + mi*16 + quad*4;
                int lc = wc*32 + ni*16 + lm;
                int gr = row0 + lr;
                int gc = col0 + lc;
                float bv = bias ? bias[gc] : 0.f;
                #pragma unroll
                for (int r = 0; r < 4; ++r) {
                    float o = acc[mi][ni][r] + Red[lr + r][lc] + bv;
                    if (ACT == 1) o = gelu_exact(o);
                    if (RESID) o += resid[(size_t)(gr + r) * ldr + gc];
                    if (OUTBF) ((unsigned short*)Cp)[(size_t)(gr + r) * ldc + gc] = f2bf(o);
                    else       ((float*)Cp)[(size_t)(gr + r) * ldc + gc] = o;
                }
            }
        }
    }
}

// ---------------- fused combine+proj-fold+merge, split-K 8-wave ----------------
// K-group 0: A = (O0+O1)/l (attention combine), W = WTfold (= Wproj@Wm_top, ld 256)
// K-group 1: A = knn_out (ld 512),              W = WTmerge+256 (knn half, ld 512)
// epilogue: + folded bias + residual -> f32 out (ld 256)
__global__ __launch_bounds__(512) void gemm64x8f(
    const unsigned short* __restrict__ Op, const float* __restrict__ Lp,
    const unsigned short* __restrict__ Akn,
    const unsigned short* __restrict__ Wat,
    const unsigned short* __restrict__ Wkn,
    const float* __restrict__ bias,
    const float* __restrict__ resid,
    float* __restrict__ Cp)
{
    __shared__ unsigned short Alds[2][64][72];
    __shared__ unsigned short Wlds[2][64][72];
    __shared__ float Red[64][68];
    const int tid = threadIdx.x;
    const int g = tid >> 8;
    const int t = tid & 255;
    const int wid2 = (tid >> 6) & 3, lane = tid & 63;
    const int lm = lane & 15, quad = lane >> 4;
    const int wr = wid2 >> 1, wc = wid2 & 1;
    const int row0 = blockIdx.y * 64, col0 = blockIdx.x * 64;
    const int ar = t >> 2, ac = (t & 3) * 16;
    const int grow = row0 + ar;

    const unsigned short* O0 = Op + (size_t)grow * 256 + ac;
    const unsigned short* O1 = Op + (size_t)(4096 + grow) * 256 + ac;
    const float* L0 = Lp + (size_t)grow * 8;
    const float* L1 = Lp + (size_t)(4096 + grow) * 8;
    const unsigned short* Ak = Akn + (size_t)grow * 512 + ac;
    const unsigned short* Wg = g ? Wkn + (size_t)(col0 + ar) * 512 + ac
                                 : Wat + (size_t)(col0 + ar) * 256 + ac;

    us8 a0, a1, o10, o11;
    float li = 0.f;
    if (g == 0) {
        a0  = *(const us8*)O0;  a1  = *(const us8*)(O0 + 8);
        o10 = *(const us8*)O1;  o11 = *(const us8*)(O1 + 8);
        li  = 1.0f / (L0[ac >> 5] + L1[ac >> 5]);
    } else {
        a0 = *(const us8*)Ak;   a1 = *(const us8*)(Ak + 8);
    }
    us8 w0 = *(const us8*)Wg;
    us8 w1 = *(const us8*)(Wg + 8);

    ffrag acc[2][2];
    #pragma unroll
    for (int mi = 0; mi < 2; ++mi)
        #pragma unroll
        for (int ni = 0; ni < 2; ++ni)
            acc[mi][ni] = (ffrag){0.f, 0.f, 0.f, 0.f};

    for (int k0 = 0;;) {
        us8 s0 = a0, s1 = a1;
        if (g == 0) {
            #pragma unroll
            for (int i = 0; i < 8; ++i) {
                s0[i] = f2bf((bf2f(a0[i]) + bf2f(o10[i])) * li);
                s1[i] = f2bf((bf2f(a1[i]) + bf2f(o11[i])) * li);
            }
        }
        __syncthreads();
        *(us8*)&Alds[g][ar][ac]   = s0;
        *(us8*)&Alds[g][ar][ac+8] = s1;
        *(us8*)&Wlds[g][ar][ac]   = w0;
        *(us8*)&Wlds[g][ar][ac+8] = w1;
        __syncthreads();
        k0 += 64;
        if (k0 < 256) {
            if (g == 0) {
                a0  = *(const us8*)(O0 + k0);  a1  = *(const us8*)(O0 + k0 + 8);
                o10 = *(const us8*)(O1 + k0);  o11 = *(const us8*)(O1 + k0 + 8);
                li  = 1.0f / (L0[(k0 + ac) >> 5] + L1[(k0 + ac) >> 5]);
            } else {
                a0 = *(const us8*)(Ak + k0);   a1 = *(const us8*)(Ak + k0 + 8);
            }
            w0 = *(const us8*)(Wg + k0);
            w1 = *(const us8*)(Wg + k0 + 8);
        }
        #pragma unroll
        for (int kc = 0; kc < 2; ++kc) {
            bfrag af[2], bw[2];
            #pragma unroll
            for (int mi = 0; mi < 2; ++mi)
                af[mi] = *(const bfrag*)&Alds[g][wr*32 + mi*16 + lm][kc*32 + quad*8];
            #pragma unroll
            for (int ni = 0; ni < 2; ++ni)
                bw[ni] = *(const bfrag*)&Wlds[g][wc*32 + ni*16 + lm][kc*32 + quad*8];
            #pragma unroll
            for (int mi = 0; mi < 2; ++mi)
                #pragma unroll
                for (int ni = 0; ni < 2; ++ni)
                    acc[mi][ni] = __builtin_amdgcn_mfma_f32_16x16x32_bf16(
                        af[mi], bw[ni], acc[mi][ni], 0, 0, 0);
        }
        if (k0 >= 256) break;
    }
    __syncthreads();
    if (g == 1) {
        #pragma unroll
        for (int mi = 0; mi < 2; ++mi)
            #pragma unroll
            for (int ni = 0; ni < 2; ++ni) {
                int lr = wr*32 + mi*16 + quad*4;
                int lc = wc*32 + ni*16 + lm;
                #pragma unroll
                for (int r = 0; r < 4; ++r)
                    Red[lr + r][lc] = acc[mi][ni][r];
            }
    }
    __syncthreads();
    if (g == 0) {
        #pragma unroll
        for (int mi = 0; mi < 2; ++mi) {
            #pragma unroll
            for (int ni = 0; ni < 2; ++ni) {
                int lr = wr*32 + mi*16 + quad*4;
                int lc = wc*32 + ni*16 + lm;
                int gr = row0 + lr;
                int gc = col0 + lc;
                float bv = bias[gc];
                #pragma unroll
                for (int r = 0; r < 4; ++r)
                    Cp[(size_t)(gr + r) * 256 + gc] =
                        acc[mi][ni][r] + Red[lr + r][lc] + bv
                        + resid[(size_t)(gr + r) * 256 + gc];
            }
        }
    }
}

// ---------------- dual-A GEMM: stage-2's two projections in one dispatch ----------------
__global__ __launch_bounds__(256) void gemm64_dual(
    const unsigned short* __restrict__ XB,
    const unsigned short* __restrict__ NVB,
    const unsigned short* __restrict__ WT2,
    const unsigned short* __restrict__ WT3,
    unsigned short* __restrict__ A2,
    unsigned short* __restrict__ A3)
{
    __shared__ unsigned short Alds[64][72];
    __shared__ unsigned short Wlds[64][72];
    const unsigned short* A; const unsigned short* Wt;
    unsigned short* C; int ldc, col0;
    if (blockIdx.x < 8) { A = XB;  Wt = WT2; C = A2; ldc = 512; col0 = blockIdx.x * 64; }
    else                { A = NVB; Wt = WT3; C = A3; ldc = 768; col0 = (blockIdx.x - 8) * 64; }
    gemm_body<0,0,1>(A, 256, Wt, nullptr, nullptr, 0, C, ldc, 256,
                     blockIdx.y * 64, col0, Alds, Wlds);
}

// ---------------- packed: flash attention (z<4) + KNN gather (z>=4) ----------------
// softmax in base-2 (log2e folded into Q weights); P packed via v_cvt_pk_bf16_f32
// into b64 LDS writes with key-permuted layout (V staged with matching permutation).
__global__ __launch_bounds__(256) void attn_gather(
    const unsigned short* __restrict__ Qp, int ldq,
    const unsigned short* __restrict__ Kp, int ldk,
    const unsigned short* __restrict__ Vp, int ldv,
    unsigned short* __restrict__ Op, float* __restrict__ Lp,
    const unsigned short* __restrict__ P, int ldp,
    const unsigned short* __restrict__ Base, int ldb,
    const float* __restrict__ gbias, const int* __restrict__ idx,
    unsigned short* __restrict__ gout, int ldgo)
{
    __shared__ unsigned short Klds[64][40];
    __shared__ __align__(16) unsigned short Vt[32][72];
    __shared__ __align__(16) unsigned short Plds[4][16][72];
    int tid = threadIdx.x, wid = tid >> 6, lane = tid & 63;

    if (blockIdx.z >= 4) {
        // ---- gather branch ----
        int gbid = blockIdx.x + 32 * (blockIdx.y + 8 * (blockIdx.z - 4));
        int q = gbid * 4 + wid;
        int b = q >> 11;
        int c = lane * 4;
        ushort4 bu = *(const ushort4*)(Base + (size_t)q * ldb + c);
        float4 bi = *(const float4*)(gbias + c);
        float bsx = bf2f(bu.x) + bi.x, bsy = bf2f(bu.y) + bi.y;
        float bsz = bf2f(bu.z) + bi.z, bsw = bf2f(bu.w) + bi.w;
        float4 acc = make_float4(-3e38f, -3e38f, -3e38f, -3e38f);
        const int* ip = idx + (size_t)q * 8;
        #pragma unroll
        for (int k = 0; k < 8; ++k) {
            int j = ip[k];
            ushort4 pu = *(const ushort4*)(P + ((size_t)(b * NKVC + j)) * ldp + c);
            float t;
            t = bsx + bf2f(pu.x); t = t > 0.f ? t : 0.2f * t; acc.x = fmaxf(acc.x, t);
            t = bsy + bf2f(pu.y); t = t > 0.f ? t : 0.2f * t; acc.y = fmaxf(acc.y, t);
            t = bsz + bf2f(pu.z); t = t > 0.f ? t : 0.2f * t; acc.z = fmaxf(acc.z, t);
            t = bsw + bf2f(pu.w); t = t > 0.f ? t : 0.2f * t; acc.w = fmaxf(acc.w, t);
        }
        ushort4 o;
        o.x = f2bf(acc.x); o.y = f2bf(acc.y); o.z = f2bf(acc.z); o.w = f2bf(acc.w);
        *(ushort4*)(gout + (size_t)q * ldgo + c) = o;
        return;
    }

    // ---- attention branch (KV-split x2, fixed-max softmax, base-2) ----
    int zc = blockIdx.z, bb = zc >> 1, ck = zc & 1;
    int h = blockIdx.y;
    int hoff = h * 32;
    int lm = lane & 15, quad = lane >> 4;
    size_t qbase  = (size_t)bb * NQC;
    size_t kvbase = (size_t)bb * NKVC;
    int q0 = blockIdx.x * 64 + wid * 16;

    bfrag aq = *(const bfrag*)(Qp + (qbase + q0 + lm) * (size_t)ldq + hoff + quad * 8);

    float l_r[4] = {0.f, 0.f, 0.f, 0.f};
    ffrag oacc[2];
    oacc[0] = (ffrag){0.f, 0.f, 0.f, 0.f};
    oacc[1] = (ffrag){0.f, 0.f, 0.f, 0.f};

    const int kkey = tid >> 2, kd0 = (tid & 3) * 8;
    const int vkey = tid & 63, vd0 = (tid >> 6) * 8;
    const int vcol = ((vkey & 15) << 2) | (vkey >> 4);   // matches P perm: key = (c&3)*16 + (c>>2)
    const unsigned short* kg0 = Kp + (kvbase + kkey) * (size_t)ldk + hoff + kd0;
    const unsigned short* vg0 = Vp + (kvbase + vkey) * (size_t)ldv + hoff + vd0;

    for (int kt = ck * 16; kt < ck * 16 + 16; ++kt) {
        us8 kv = *(const us8*)(kg0 + (size_t)kt * 64 * ldk);
        us8 vv = *(const us8*)(vg0 + (size_t)kt * 64 * ldv);
        __syncthreads();
        *(us8*)&Klds[kkey][kd0] = kv;
        #pragma unroll
        for (int i = 0; i < 8; ++i) Vt[vd0 + i][vcol] = vv[i];
        __syncthreads();

        ffrag sacc[4];
        #pragma unroll
        for (int t = 0; t < 4; ++t) {
            bfrag bk = *(const bfrag*)&Klds[t*16 + lm][quad * 8];
            sacc[t] = __builtin_amdgcn_mfma_f32_16x16x32_bf16(
                aq, bk, (ffrag){0.f,0.f,0.f,0.f}, 0, 0, 0);
        }

        #pragma unroll
        for (int r = 0; r < 4; ++r) {
            float p0 = fexp2(sacc[0][r]), p1 = fexp2(sacc[1][r]);
            float p2 = fexp2(sacc[2][r]), p3 = fexp2(sacc[3][r]);
            l_r[r] += (p0 + p1) + (p2 + p3);
            unsigned u0 = cvt_pk_bf16(p0, p1);
            unsigned u1 = cvt_pk_bf16(p2, p3);
            *(uint2*)&Plds[wid][quad*4 + r][lm << 2] = make_uint2(u0, u1);
        }
        asm volatile("s_waitcnt lgkmcnt(0)" ::: "memory");  // wave-private P RAW

        #pragma unroll
        for (int kc = 0; kc < 2; ++kc) {
            bfrag ap = *(const bfrag*)&Plds[wid][lm][kc*32 + quad*8];
            #pragma unroll
            for (int nt = 0; nt < 2; ++nt) {
                bfrag bv = *(const bfrag*)&Vt[nt*16 + lm][kc*32 + quad*8];
                oacc[nt] = __builtin_amdgcn_mfma_f32_16x16x32_bf16(
                    ap, bv, oacc[nt], 0, 0, 0);
            }
        }
    }
    #pragma unroll
    for (int nt = 0; nt < 2; ++nt)
        #pragma unroll
        for (int r = 0; r < 4; ++r)
            Op[((size_t)ck * 4096 + qbase + q0 + quad*4 + r) * 256 + hoff + nt*16 + lm]
                = f2bf(oacc[nt][r]);
    #pragma unroll
    for (int r = 0; r < 4; ++r) {
        float l = l_r[r];
        l += __shfl_xor(l, 1);
        l += __shfl_xor(l, 2);
        l += __shfl_xor(l, 4);
        l += __shfl_xor(l, 8);
        if (lm == 0)
            Lp[((size_t)ck * 4096 + qbase + q0 + quad*4 + r) * 8 + h] = l;
    }
}

extern "C" void kernel_launch(void* const* d_in, const int* in_sizes, int n_in,
                              void* d_out, int out_size, void* d_ws, size_t ws_size,
                              hipStream_t stream) {
    const float* q_in   = (const float*)d_in[0];
    const float* v_in   = (const float*)d_in[1];
    const int*   idx_s  = (const int*)d_in[4];
    const int*   idx_x  = (const int*)d_in[5];
    const float* n1g = (const float*)d_in[6],  *n1b = (const float*)d_in[7];
    const float* nqg = (const float*)d_in[8],  *nqb = (const float*)d_in[9];
    const float* nvg = (const float*)d_in[10], *nvb = (const float*)d_in[11];
    const float* n2g = (const float*)d_in[12], *n2b = (const float*)d_in[13];
    const float* sa_qkv_w  = (const float*)d_in[14];
    const float* sa_proj_w = (const float*)d_in[15];
    const float* sa_proj_b = (const float*)d_in[16];
    const float* ca_q_w    = (const float*)d_in[17];
    const float* ca_kv_w   = (const float*)d_in[18];
    const float* ca_proj_w = (const float*)d_in[19];
    const float* ca_proj_b = (const float*)d_in[20];
    const float* fc1_w = (const float*)d_in[21], *fc1_b = (const float*)d_in[22];
    const float* fc2_w = (const float*)d_in[23], *fc2_b = (const float*)d_in[24];
    const float* knn_w   = (const float*)d_in[25], *knn_b   = (const float*)d_in[26];
    const float* merge_w = (const float*)d_in[27], *merge_b = (const float*)d_in[28];
    const float* knnx_w  = (const float*)d_in[29], *knnx_b  = (const float*)d_in[30];
    const float* mergex_w = (const float*)d_in[31], *mergex_b = (const float*)d_in[32];
    float* out = (float*)d_out;

    unsigned short* A1      = (unsigned short*)d_ws;           // 4096x1280 bf16
    unsigned short* A2      = A1;                              // 4096x512 (stage2 overlay)
    unsigned short* A3      = A1 + (size_t)4096 * 512;         // 4096x768 (stage2 overlay)
    unsigned short* Hb      = A1;                              // 4096x1024 (stage3 overlay)
    unsigned short* KN      = A1 + (size_t)4096 * 1280;        // 4096x256 knn_out (CC+256 view)
    unsigned short* CC      = KN;                              // 4096x512 [unused | knn_out]
    unsigned short* XB      = CC + (size_t)4096 * 512;         // 4096x256 LN out
    unsigned short* NVB     = XB + (size_t)4096 * 256;         // 4096x256 LN(v)
    unsigned short* WT      = NVB + (size_t)4096 * 256;        // weights, 1572864 us
    unsigned short* WT1     = WT;
    unsigned short* projbf  = WT + 327680;                     // proj bf16 [k][n] linear
    unsigned short* WTmerge = WT + 393216;
    unsigned short* WT2     = WT + 524288;
    unsigned short* WT3     = WT + 655360;
    unsigned short* projxbf = WT + 851968;                     // projx bf16 [k][n] linear
    unsigned short* WTmergex= WT + 917504;
    unsigned short* WTfc1   = WT + 1048576;
    unsigned short* WTfc2   = WT + 1310720;
    unsigned short* Opart   = WT + 1572864;                    // [2][4096][256] bf16
    float* Lpart = (float*)(Opart + (size_t)2 * 4096 * 256);   // [2][4096][8]  f32
    unsigned short* WTf1 = (unsigned short*)(Lpart + (size_t)2 * 4096 * 8);  // [256][256]
    unsigned short* WTfx = WTf1 + 65536;                                     // [256][256]
    float* bf1 = (float*)(WTfx + 65536);                       // folded bias stage1 [256]
    float* bfx = bf1 + 256;                                    // folded bias stage2 [256]

    dim3 blk(256), blk8(512);
    dim3 gAG(NQC / 64, 8, 8);     // z<4: attn (b*2+ck); z>=4: gather

    // prep: tiled-transpose weights + copies + LN(q) + LN(v) + bias folds
    prep_w<<<dim3(2530), blk, 0, stream>>>(sa_qkv_w, knn_w, sa_proj_w, merge_w,
        ca_q_w, knnx_w, ca_kv_w, ca_proj_w, mergex_w, fc1_w, fc2_w, WT,
        q_in, n1g, n1b, XB,
        v_in, nvg, nvb, NVB,
        sa_proj_b, merge_b, bf1,
        ca_proj_b, mergex_b, bfx);

    // ---- stage 1 ----
    gemm_qkv_fold<<<dim3(20,66), blk, 0, stream>>>(XB, WT1, A1,
        WTmerge, projbf, WTf1, WTmergex, projxbf, WTfx);                            // [qkv|P|Base] + folds
    attn_gather<<<gAG, blk, 0, stream>>>(A1, 1280, A1+256, 1280, A1+512, 1280,
        Opart, Lpart, A1+768, 1280, A1+1024, 1280, knn_b, idx_s, CC+256, 512);
    gemm64x8f<<<dim3(4,64), blk8, 0, stream>>>(Opart, Lpart, CC+256,
        WTf1, WTmerge+256, bf1, q_in, out);                                         // q = q + merge(fused)

    // ---- stage 2 ----
    ln_b<<<dim3(1024), blk, 0, stream>>>(out, nqg, nqb, XB);                        // nq2
    gemm64_dual<<<dim3(20,64), blk, 0, stream>>>(XB, NVB, WT2, WT3, A2, A3);        // both projections
    attn_gather<<<gAG, blk, 0, stream>>>(A2, 512, A3, 768, A3+256, 768,
        Opart, Lpart, A3+512, 768, A2+256, 512, knnx_b, idx_x, CC+256, 512);
    gemm64x8f<<<dim3(4,64), blk8, 0, stream>>>(Opart, Lpart, CC+256,
        WTfx, WTmergex+256, bfx, out, out);                                         // q = q + mergex(fused)

    // ---- stage 3 ----
    ln_b<<<dim3(1024), blk, 0, stream>>>(out, n2g, n2b, XB);                        // h = LN(q)
    gemm64<1,0,1><<<dim3(16,64), blk, 0, stream>>>(XB, 256, WTfc1,
        fc1_b, nullptr, 0, Hb, 1024, 256);                                          // gelu(LN(q)@fc1+b)
    gemm64x8<0,1,0><<<dim3(4,64), blk8, 0, stream>>>(Hb, 1024, WTfc2,
        fc2_b, out, 256, out, 256, 1024);                                           // q += fc2
}

// Round 10
// 235.550 us; speedup vs baseline: 1.2201x; 1.0055x over previous
//
#include <hip/hip_runtime.h>
#include <math.h>

#define NQC   2048
#define NKVC  2048
#define DIMC  256
// 1/sqrt(32) * log2(e): attention scale with exp->exp2 base change folded in
#define SCALEF 0.2550348810731232f

typedef short bfrag __attribute__((ext_vector_type(8)));   // 8 bf16 = 4 VGPRs
typedef float ffrag __attribute__((ext_vector_type(4)));   // MFMA C/D
typedef unsigned short us8 __attribute__((ext_vector_type(8)));

__device__ __forceinline__ float gelu_exact(float x) {
    return 0.5f * x * (1.0f + erff(x * 0.70710678118654752f));
}
__device__ __forceinline__ unsigned short f2bf(float f) {
    union { float f; unsigned u; } v; v.f = f;
    unsigned r = v.u + 0x7FFFu + ((v.u >> 16) & 1u);   // RNE
    return (unsigned short)(r >> 16);
}
__device__ __forceinline__ float bf2f(unsigned short u) {
    union { unsigned u; float f; } v; v.u = ((unsigned)u) << 16;
    return v.f;
}
__device__ __forceinline__ float fexp2(float x) {
    float r; asm("v_exp_f32 %0, %1" : "=v"(r) : "v"(x)); return r;
}
__device__ __forceinline__ unsigned cvt_pk_bf16(float lo, float hi) {
    unsigned r; asm("v_cvt_pk_bf16_f32 %0, %1, %2" : "=v"(r) : "v"(lo), "v"(hi));
    return r;
}

// ---------------- LN device body (one wave per row) ----------------
__device__ __forceinline__ void ln_row(
    const float* __restrict__ x, const float* __restrict__ g,
    const float* __restrict__ b, unsigned short* __restrict__ y, int row)
{
    int lane = threadIdx.x & 63;
    const float* xr = x + (size_t)row * DIMC + lane * 4;
    float4 vv = *(const float4*)xr;
    float s  = vv.x + vv.y + vv.z + vv.w;
    float sq = vv.x*vv.x + vv.y*vv.y + vv.z*vv.z + vv.w*vv.w;
    #pragma unroll
    for (int off = 32; off >= 1; off >>= 1) {
        s  += __shfl_xor(s, off);
        sq += __shfl_xor(sq, off);
    }
    float mean = s * (1.0f/DIMC);
    float inv  = rsqrtf(sq * (1.0f/DIMC) - mean*mean + 1e-5f);
    float4 gg = *(const float4*)(g + lane*4);
    float4 bb = *(const float4*)(b + lane*4);
    ushort4 o;
    o.x = f2bf((vv.x - mean) * inv * gg.x + bb.x);
    o.y = f2bf((vv.y - mean) * inv * gg.y + bb.y);
    o.z = f2bf((vv.z - mean) * inv * gg.z + bb.z);
    o.w = f2bf((vv.w - mean) * inv * gg.w + bb.w);
    *(ushort4*)(y + (size_t)row * DIMC + lane * 4) = o;
}

// ---------------- packed prep: tiled-transpose weights + copies + LN(q) + LN(v) + folds
// blocks 0..351:    64x64 weight tiles, coalesced load -> LDS transpose -> coalesced store
// blocks 352..479:  linear bf16 copies (projbf, projxbf)
// blocks 480..1503: LN(q) -> XB
// blocks 1504..2527:LN(v) -> NVB
// blocks 2528..2529:folded biases
__global__ __launch_bounds__(256) void prep_w(
    const float* __restrict__ qkv, const float* __restrict__ knn,
    const float* __restrict__ proj, const float* __restrict__ merge,
    const float* __restrict__ caq, const float* __restrict__ knnx,
    const float* __restrict__ cakv, const float* __restrict__ projx,
    const float* __restrict__ mergex, const float* __restrict__ fc1,
    const float* __restrict__ fc2, unsigned short* __restrict__ dst,
    const float* __restrict__ lx, const float* __restrict__ lg,
    const float* __restrict__ lb, unsigned short* __restrict__ ly,
    const float* __restrict__ vx, const float* __restrict__ vg,
    const float* __restrict__ vb, unsigned short* __restrict__ vy,
    const float* __restrict__ pb1, const float* __restrict__ mb1, float* __restrict__ bf1o,
    const float* __restrict__ pbx, const float* __restrict__ mbx, float* __restrict__ bfxo)
{
    __shared__ unsigned short T[64][72];
    int blk = blockIdx.x, tid = threadIdx.x;
    if (blk >= 2528) {
        // folded bias: bfold[m] = merge_b[m] + sum_k proj_b[k] * merge_w[k][m]
        const float* bp = (blk == 2528) ? pb1 : pbx;
        const float* Wm = (blk == 2528) ? merge : mergex;
        const float* bm = (blk == 2528) ? mb1 : mbx;
        float* o        = (blk == 2528) ? bf1o : bfxo;
        int m = tid;
        float acc = bm[m];
        for (int k = 0; k < 256; ++k) acc += bp[k] * Wm[(size_t)k * 256 + m];
        o[m] = acc;
        return;
    }
    if (blk >= 1504) {   // LN(v)
        ln_row(vx, vg, vb, vy, (blk - 1504) * 4 + (tid >> 6));
        return;
    }
    if (blk >= 480) {    // LN(q)
        ln_row(lx, lg, lb, ly, (blk - 480) * 4 + (tid >> 6));
        return;
    }
    if (blk >= 352) {    // linear copies (already [k][n]-major in both layouts)
        int l = blk - 352;
        const float* s; unsigned short* d;
        if (l < 64) { s = proj;  d = dst + 327680; }
        else        { s = projx; d = dst + 851968; l -= 64; }
        int e = (l * 256 + tid) * 4;
        float4 v = *(const float4*)(s + e);
        ushort4 o;
        o.x = f2bf(v.x); o.y = f2bf(v.y); o.z = f2bf(v.z); o.w = f2bf(v.w);
        *(ushort4*)(d + e) = o;
        return;
    }
    // ---- 64x64 transpose tile: dst[n][k] <- src[k][n] (optionally minus src2, scaled)
    int t = blk;
    const float* src; const float* src2 = nullptr; int sN;
    unsigned short* dp; int dK; float scale = 1.0f; int n0, k0;
    if (t < 48)       { src = qkv;          sN = 768;  dp = dst;           dK = 256;
                        n0 = (t % 12) * 64; k0 = (t / 12) * 64; if (n0 < 256) scale = SCALEF; }
    else if (t < 64)  { int u = t - 48;  src = knn;          sN = 256; dp = dst + 196608; dK = 256;
                        n0 = (u & 3) * 64; k0 = (u >> 2) * 64; }             // knn lo -> WT1 rows 768..1024
    else if (t < 80)  { int u = t - 64;  src = knn + 65536;  src2 = knn; sN = 256; dp = dst + 262144; dK = 256;
                        n0 = (u & 3) * 64; k0 = (u >> 2) * 64; }             // knn hi-lo -> rows 1024..1280
    else if (t < 112) { int u = t - 80;  src = merge;        sN = 256; dp = dst + 393216; dK = 512;
                        n0 = (u & 3) * 64; k0 = (u >> 2) * 64; }
    else if (t < 128) { int u = t - 112; src = caq;          sN = 256; dp = dst + 524288; dK = 256;
                        n0 = (u & 3) * 64; k0 = (u >> 2) * 64; scale = SCALEF; }
    else if (t < 144) { int u = t - 128; src = knnx + 65536; src2 = knnx; sN = 256; dp = dst + 589824; dK = 256;
                        n0 = (u & 3) * 64; k0 = (u >> 2) * 64; }             // WT2 rows 256..512
    else if (t < 176) { int u = t - 144; src = cakv;         sN = 512; dp = dst + 655360; dK = 256;
                        n0 = (u & 7) * 64; k0 = (u >> 3) * 64; }
    else if (t < 192) { int u = t - 176; src = knnx;         sN = 256; dp = dst + 786432; dK = 256;
                        n0 = (u & 3) * 64; k0 = (u >> 2) * 64; }             // WT3 rows 512..768
    else if (t < 224) { int u = t - 192; src = mergex;       sN = 256; dp = dst + 917504; dK = 512;
                        n0 = (u & 3) * 64; k0 = (u >> 2) * 64; }
    else if (t < 288) { int u = t - 224; src = fc1;          sN = 1024; dp = dst + 1048576; dK = 256;
                        n0 = (u & 15) * 64; k0 = (u >> 4) * 64; }
    else              { int u = t - 288; src = fc2;          sN = 256; dp = dst + 1310720; dK = 1024;
                        n0 = (u & 3) * 64; k0 = (u >> 2) * 64; }
    int r = tid >> 2, c0 = (tid & 3) * 16;
    float va[16];
    {
        const float* sp = src + (size_t)(k0 + r) * sN + n0 + c0;
        float4 f0 = *(const float4*)(sp);
        float4 f1 = *(const float4*)(sp + 4);
        float4 f2 = *(const float4*)(sp + 8);
        float4 f3 = *(const float4*)(sp + 12);
        va[0]=f0.x; va[1]=f0.y; va[2]=f0.z;  va[3]=f0.w;
        va[4]=f1.x; va[5]=f1.y; va[6]=f1.z;  va[7]=f1.w;
        va[8]=f2.x; va[9]=f2.y; va[10]=f2.z; va[11]=f2.w;
        va[12]=f3.x; va[13]=f3.y; va[14]=f3.z; va[15]=f3.w;
        if (src2) {
            const float* s2 = src2 + (size_t)(k0 + r) * sN + n0 + c0;
            float4 h0 = *(const float4*)(s2);
            float4 h1 = *(const float4*)(s2 + 4);
            float4 h2 = *(const float4*)(s2 + 8);
            float4 h3 = *(const float4*)(s2 + 12);
            va[0]-=h0.x; va[1]-=h0.y; va[2]-=h0.z;  va[3]-=h0.w;
            va[4]-=h1.x; va[5]-=h1.y; va[6]-=h1.z;  va[7]-=h1.w;
            va[8]-=h2.x; va[9]-=h2.y; va[10]-=h2.z; va[11]-=h2.w;
            va[12]-=h3.x; va[13]-=h3.y; va[14]-=h3.z; va[15]-=h3.w;
        }
    }
    #pragma unroll
    for (int i = 0; i < 16; ++i) T[c0 + i][r] = f2bf(va[i] * scale);
    __syncthreads();
    {
        int n = tid >> 2, kk = (tid & 3) * 16;
        unsigned short* d = dp + (size_t)(n0 + n) * dK + k0 + kk;
        *(us8*)d       = *(const us8*)&T[n][kk];
        *(us8*)(d + 8) = *(const us8*)&T[n][kk + 8];
    }
}

// ---------------- bf16 MFMA GEMM body, 64x64 tile, BK=64 ----------------
template<int ACT, int RESID, int OUTBF>
__device__ __forceinline__ void gemm_body(
    const unsigned short* __restrict__ A, int lda,
    const unsigned short* __restrict__ Wt,
    const float* __restrict__ bias,
    const float* __restrict__ resid, int ldr,
    void* __restrict__ Cp, int ldc, int Kc, int row0, int col0,
    unsigned short (* __restrict__ Alds)[72],
    unsigned short (* __restrict__ Wlds)[72])
{
    const int tid = threadIdx.x;
    const int wid = tid >> 6, lane = tid & 63;
    const int lm = lane & 15, quad = lane >> 4;
    const int wr = wid >> 1, wc = wid & 1;
    const int ar = tid >> 2, ac = (tid & 3) * 16;
    const unsigned short* Ag = A  + (size_t)(row0 + ar) * lda + ac;
    const unsigned short* Wg = Wt + (size_t)(col0 + ar) * Kc  + ac;

    us8 a0 = *(const us8*)Ag;
    us8 a1 = *(const us8*)(Ag + 8);
    us8 w0 = *(const us8*)Wg;
    us8 w1 = *(const us8*)(Wg + 8);

    ffrag acc[2][2];
    #pragma unroll
    for (int mi = 0; mi < 2; ++mi)
        #pragma unroll
        for (int ni = 0; ni < 2; ++ni)
            acc[mi][ni] = (ffrag){0.f, 0.f, 0.f, 0.f};

    for (int k0 = 0;;) {
        __syncthreads();
        *(us8*)&Alds[ar][ac]   = a0;
        *(us8*)&Alds[ar][ac+8] = a1;
        *(us8*)&Wlds[ar][ac]   = w0;
        *(us8*)&Wlds[ar][ac+8] = w1;
        __syncthreads();
        k0 += 64;
        if (k0 < Kc) {
            a0 = *(const us8*)(Ag + k0);
            a1 = *(const us8*)(Ag + k0 + 8);
            w0 = *(const us8*)(Wg + k0);
            w1 = *(const us8*)(Wg + k0 + 8);
        }
        #pragma unroll
        for (int kc = 0; kc < 2; ++kc) {
            bfrag af[2], bw[2];
            #pragma unroll
            for (int mi = 0; mi < 2; ++mi)
                af[mi] = *(const bfrag*)&Alds[wr*32 + mi*16 + lm][kc*32 + quad*8];
            #pragma unroll
            for (int ni = 0; ni < 2; ++ni)
                bw[ni] = *(const bfrag*)&Wlds[wc*32 + ni*16 + lm][kc*32 + quad*8];
            #pragma unroll
            for (int mi = 0; mi < 2; ++mi)
                #pragma unroll
                for (int ni = 0; ni < 2; ++ni)
                    acc[mi][ni] = __builtin_amdgcn_mfma_f32_16x16x32_bf16(
                        af[mi], bw[ni], acc[mi][ni], 0, 0, 0);
        }
        if (k0 >= Kc) break;
    }
    #pragma unroll
    for (int mi = 0; mi < 2; ++mi) {
        #pragma unroll
        for (int ni = 0; ni < 2; ++ni) {
            int gr = row0 + wr*32 + mi*16 + quad*4;
            int gc = col0 + wc*32 + ni*16 + lm;
            float bv = bias ? bias[gc] : 0.f;
            #pragma unroll
            for (int r = 0; r < 4; ++r) {
                float o = acc[mi][ni][r] + bv;
                if (ACT == 1) o = gelu_exact(o);
                if (RESID) o += resid[(size_t)(gr + r) * ldr + gc];
                if (OUTBF) ((unsigned short*)Cp)[(size_t)(gr + r) * ldc + gc] = f2bf(o);
                else       ((float*)Cp)[(size_t)(gr + r) * ldc + gc] = o;
            }
        }
    }
}

template<int ACT, int RESID, int OUTBF>
__global__ __launch_bounds__(256) void gemm64(
    const unsigned short* __restrict__ A, int lda,
    const unsigned short* __restrict__ Wt,
    const float* __restrict__ bias,
    const float* __restrict__ resid, int ldr,
    void* __restrict__ Cp, int ldc, int Kc)
{
    __shared__ unsigned short Alds[64][72];
    __shared__ unsigned short Wlds[64][72];
    gemm_body<ACT,RESID,OUTBF>(A, lda, Wt, bias, resid, ldr, Cp, ldc, Kc,
                               blockIdx.y * 64, blockIdx.x * 64, Alds, Wlds);
}

// ---------------- qkv GEMM + packed weight-fold GEMMs (WTfold = Wproj @ Wm_top) ----------
// y<64: qkv [4096x1280]; y==64: fold1 (16 blocks); y==65: foldx (16 blocks)
__global__ __launch_bounds__(256) void gemm_qkv_fold(
    const unsigned short* __restrict__ XB, const unsigned short* __restrict__ WT1,
    unsigned short* __restrict__ A1,
    const unsigned short* __restrict__ WTmerge, const unsigned short* __restrict__ projbf,
    unsigned short* __restrict__ WTf1,
    const unsigned short* __restrict__ WTmergex, const unsigned short* __restrict__ projxbf,
    unsigned short* __restrict__ WTfx)
{
    __shared__ unsigned short Alds[64][72];
    __shared__ unsigned short Wlds[64][72];
    const unsigned short *A, *Wt; unsigned short* C;
    int lda, ldc, row0, col0;
    if (blockIdx.y >= 64) {
        if (blockIdx.x >= 16) return;
        row0 = (blockIdx.x >> 2) * 64; col0 = (blockIdx.x & 3) * 64;
        lda = 512; ldc = 256;
        if (blockIdx.y == 64) { A = WTmerge;  Wt = projbf;  C = WTf1; }
        else                  { A = WTmergex; Wt = projxbf; C = WTfx; }
    } else {
        A = XB; Wt = WT1; C = A1; lda = 256; ldc = 1280;
        row0 = blockIdx.y * 64; col0 = blockIdx.x * 64;
    }
    gemm_body<0,0,1>(A, lda, Wt, nullptr, nullptr, 0, C, ldc, 256, row0, col0, Alds, Wlds);
}

// ---------------- split-K 8-wave GEMM (fc2) ----------------
template<int ACT, int RESID, int OUTBF>
__global__ __launch_bounds__(512) void gemm64x8(
    const unsigned short* __restrict__ A, int lda,
    const unsigned short* __restrict__ Wt,
    const float* __restrict__ bias,
    const float* __restrict__ resid, int ldr,
    void* __restrict__ Cp, int ldc, int Kc)
{
    __shared__ unsigned short Alds[2][64][72];
    __shared__ unsigned short Wlds[2][64][72];
    __shared__ float Red[64][68];
    const int tid = threadIdx.x;
    const int g = tid >> 8;
    const int t = tid & 255;
    const int wid2 = (tid >> 6) & 3, lane = tid & 63;
    const int lm = lane & 15, quad = lane >> 4;
    const int wr = wid2 >> 1, wc = wid2 & 1;
    const int row0 = blockIdx.y * 64, col0 = blockIdx.x * 64;
    const int ar = t >> 2, ac = (t & 3) * 16;
    const int KH = Kc >> 1;
    const unsigned short* Ag = A  + (size_t)(row0 + ar) * lda + g * KH + ac;
    const unsigned short* Wg = Wt + (size_t)(col0 + ar) * Kc  + g * KH + ac;

    us8 a0 = *(const us8*)Ag;
    us8 a1 = *(const us8*)(Ag + 8);
    us8 w0 = *(const us8*)Wg;
    us8 w1 = *(const us8*)(Wg + 8);

    ffrag acc[2][2];
    #pragma unroll
    for (int mi = 0; mi < 2; ++mi)
        #pragma unroll
        for (int ni = 0; ni < 2; ++ni)
            acc[mi][ni] = (ffrag){0.f, 0.f, 0.f, 0.f};

    for (int k0 = 0;;) {
        __syncthreads();
        *(us8*)&Alds[g][ar][ac]   = a0;
        *(us8*)&Alds[g][ar][ac+8] = a1;
        *(us8*)&Wlds[g][ar][ac]   = w0;
        *(us8*)&Wlds[g][ar][ac+8] = w1;
        __syncthreads();
        k0 += 64;
        if (k0 < KH) {
            a0 = *(const us8*)(Ag + k0);
            a1 = *(const us8*)(Ag + k0 + 8);
            w0 = *(const us8*)(Wg + k0);
            w1 = *(const us8*)(Wg + k0 + 8);
        }
        #pragma unroll
        for (int kc = 0; kc < 2; ++kc) {
            bfrag af[2], bw[2];
            #pragma unroll
            for (int mi = 0; mi < 2; ++mi)
                af[mi] = *(const bfrag*)&Alds[g][wr*32 + mi*16 + lm][kc*32 + quad*8];
            #pragma unroll
            for (int ni = 0; ni < 2; ++ni)
                bw[ni] = *(const bfrag*)&Wlds[g][wc*32 + ni*16 + lm][kc*32 + quad*8];
            #pragma unroll
            for (int mi = 0; mi < 2; ++mi)
                #pragma unroll
                for (int ni = 0; ni < 2; ++ni)
                    acc[mi][ni] = __builtin_amdgcn_mfma_f32_16x16x32_bf16(
                        af[mi], bw[ni], acc[mi][ni], 0, 0, 0);
        }
        if (k0 >= KH) break;
    }
    __syncthreads();
    if (g == 1) {
        #pragma unroll
        for (int mi = 0; mi < 2; ++mi)
            #pragma unroll
            for (int ni = 0; ni < 2; ++ni) {
                int lr = wr*32 + mi*16 + quad*4;
                int lc = wc*32 + ni*16 + lm;
                #pragma unroll
                for (int r = 0; r < 4; ++r)
                    Red[lr + r][lc] = acc[mi][ni][r];
            }
    }
    __syncthreads();
    if (g == 0) {
        #pragma unroll
        for (int mi = 0; mi < 2; ++mi) {
            #pragma unroll
            for (int ni = 0; ni < 2; ++ni) {
                int lr = wr*32 + mi*16 + quad*4;
                int lc = wc*32 + ni*16 + lm;
                int gr = row0 + lr;
                int gc = col0 + lc;
                float bv = bias ? bias[gc] : 0.f;
                #pragma unroll
                for (int r = 0; r < 4; ++r) {
                    float o = acc[mi][ni][r] + Red[lr + r][lc] + bv;
                    if (ACT == 1) o = gelu_exact(o);
                    if (RESID) o += resid[(size_t)(gr + r) * ldr + gc];
                    if (OUTBF) ((unsigned short*)Cp)[(size_t)(gr + r) * ldc + gc] = f2bf(o);
                    else       ((float*)Cp)[(size_t)(gr + r) * ldc + gc] = o;
                }
            }
        }
    }
}

// ---------------- fused merge GEMM + row-LN, row-stripe blocks ----------------
// Block = 16 rows x 256 cols (full width), 8 waves each 16x32; K=512 serial:
// k<256: A = (O0+O1)/l combine, W = WTfold (ld 256); k>=256: A = knn_out
// (ld 512), W = merge knn-half (ld 512, cols 256..511). Epilogue: +folded bias
// +residual -> f32 out, then block-local row LayerNorm -> bf16 ln_out. Kills the
// ln_b dispatch (one block owns full 256-wide rows so stats are block-local).
__global__ __launch_bounds__(512) void gemm_mln(
    const unsigned short* __restrict__ Op, const float* __restrict__ Lp,
    const unsigned short* __restrict__ Akn,
    const unsigned short* __restrict__ Wat,
    const unsigned short* __restrict__ Wkn,
    const float* __restrict__ bias,
    const float* __restrict__ resid,
    float* __restrict__ Cp,
    const float* __restrict__ lng, const float* __restrict__ lnb,
    unsigned short* __restrict__ ln_out)
{
    __shared__ unsigned short Wlds[256][72];
    __shared__ unsigned short Alds[16][72];
    __shared__ float OutT[16][268];
    const int tid = threadIdx.x;
    const int wid = tid >> 6, lane = tid & 63;
    const int lm = lane & 15, quad = lane >> 4;
    const int row0 = blockIdx.x * 16;
    const int wn = tid >> 1, wk = (tid & 1) * 32;      // W staging: 256n x 64k
    const int ar = tid >> 3, ac = (tid & 7) * 8;       // A staging: 16r x 64k (tid<128)

    const unsigned short* O0 = Op + (size_t)(row0 + ar) * 256 + ac;
    const unsigned short* O1 = Op + (size_t)(4096 + row0 + ar) * 256 + ac;
    const float* L0 = Lp + (size_t)(row0 + ar) * 8;
    const float* L1 = Lp + (size_t)(4096 + row0 + ar) * 8;
    const unsigned short* Ak = Akn + (size_t)(row0 + ar) * 512 + ac;

    us8 aReg, wv0, wv1, wv2, wv3;
    if (tid < 128) {
        us8 x = *(const us8*)O0;
        us8 y = *(const us8*)O1;
        float li = 1.0f / (L0[ac >> 5] + L1[ac >> 5]);
        #pragma unroll
        for (int i = 0; i < 8; ++i)
            aReg[i] = f2bf((bf2f(x[i]) + bf2f(y[i])) * li);
    }
    {
        const unsigned short* Wg = Wat + (size_t)wn * 256 + wk;
        wv0 = *(const us8*)Wg;        wv1 = *(const us8*)(Wg + 8);
        wv2 = *(const us8*)(Wg + 16); wv3 = *(const us8*)(Wg + 24);
    }

    ffrag acc[2];
    acc[0] = (ffrag){0.f, 0.f, 0.f, 0.f};
    acc[1] = (ffrag){0.f, 0.f, 0.f, 0.f};

    for (int k0 = 0;;) {
        __syncthreads();
        if (tid < 128) *(us8*)&Alds[ar][ac] = aReg;
        *(us8*)&Wlds[wn][wk]      = wv0;
        *(us8*)&Wlds[wn][wk + 8]  = wv1;
        *(us8*)&Wlds[wn][wk + 16] = wv2;
        *(us8*)&Wlds[wn][wk + 24] = wv3;
        __syncthreads();
        k0 += 64;
        if (k0 < 512) {
            if (tid < 128) {
                if (k0 < 256) {
                    us8 x = *(const us8*)(O0 + k0);
                    us8 y = *(const us8*)(O1 + k0);
                    float li = 1.0f / (L0[(k0 + ac) >> 5] + L1[(k0 + ac) >> 5]);
                    #pragma unroll
                    for (int i = 0; i < 8; ++i)
                        aReg[i] = f2bf((bf2f(x[i]) + bf2f(y[i])) * li);
                } else {
                    aReg = *(const us8*)(Ak + (k0 - 256));
                }
            }
            const unsigned short* Wg = (k0 < 256)
                ? Wat + (size_t)wn * 256 + k0 + wk
                : Wkn + (size_t)wn * 512 + (k0 - 256) + wk;
            wv0 = *(const us8*)Wg;        wv1 = *(const us8*)(Wg + 8);
            wv2 = *(const us8*)(Wg + 16); wv3 = *(const us8*)(Wg + 24);
        }
        #pragma unroll
        for (int kc = 0; kc < 2; ++kc) {
            bfrag af = *(const bfrag*)&Alds[lm][kc*32 + quad*8];
            #pragma unroll
            for (int ni = 0; ni < 2; ++ni) {
                bfrag bw = *(const bfrag*)&Wlds[wid*32 + ni*16 + lm][kc*32 + quad*8];
                acc[ni] = __builtin_amdgcn_mfma_f32_16x16x32_bf16(
                    af, bw, acc[ni], 0, 0, 0);
            }
        }
        if (k0 >= 512) break;
    }
    // epilogue: bias + residual -> global f32 out + LDS row tile
    #pragma unroll
    for (int ni = 0; ni < 2; ++ni) {
        int gc = wid*32 + ni*16 + lm;
        float bv = bias[gc];
        #pragma unroll
        for (int r = 0; r < 4; ++r) {
            int lr = quad*4 + r;
            float o = acc[ni][r] + bv + resid[(size_t)(row0 + lr) * 256 + gc];
            Cp[(size_t)(row0 + lr) * 256 + gc] = o;
            OutT[lr][gc] = o;
        }
    }
    __syncthreads();
    // row LayerNorm: wave wid handles rows 2*wid and 2*wid+1 (identical math to ln_row)
    #pragma unroll
    for (int rr0 = 0; rr0 < 2; ++rr0) {
        int rr = wid * 2 + rr0;
        float4 vv = *(const float4*)&OutT[rr][lane * 4];
        float s  = vv.x + vv.y + vv.z + vv.w;
        float sq = vv.x*vv.x + vv.y*vv.y + vv.z*vv.z + vv.w*vv.w;
        #pragma unroll
        for (int off = 32; off >= 1; off >>= 1) {
            s  += __shfl_xor(s, off);
            sq += __shfl_xor(sq, off);
        }
        float mean = s * (1.0f/DIMC);
        float inv  = rsqrtf(sq * (1.0f/DIMC) - mean*mean + 1e-5f);
        float4 gg = *(const float4*)(lng + lane*4);
        float4 bb = *(const float4*)(lnb + lane*4);
        ushort4 o;
        o.x = f2bf((vv.x - mean) * inv * gg.x + bb.x);
        o.y = f2bf((vv.y - mean) * inv * gg.y + bb.y);
        o.z = f2bf((vv.z - mean) * inv * gg.z + bb.z);
        o.w = f2bf((vv.w - mean) * inv * gg.w + bb.w);
        *(ushort4*)(ln_out + (size_t)(row0 + rr) * 256 + lane * 4) = o;
    }
}

// ---------------- dual-A GEMM: stage-2's two projections in one dispatch ----------------
__global__ __launch_bounds__(256) void gemm64_dual(
    const unsigned short* __restrict__ XB,
    const unsigned short* __restrict__ NVB,
    const unsigned short* __restrict__ WT2,
    const unsigned short* __restrict__ WT3,
    unsigned short* __restrict__ A2,
    unsigned short* __restrict__ A3)
{
    __shared__ unsigned short Alds[64][72];
    __shared__ unsigned short Wlds[64][72];
    const unsigned short* A; const unsigned short* Wt;
    unsigned short* C; int ldc, col0;
    if (blockIdx.x < 8) { A = XB;  Wt = WT2; C = A2; ldc = 512; col0 = blockIdx.x * 64; }
    else                { A = NVB; Wt = WT3; C = A3; ldc = 768; col0 = (blockIdx.x - 8) * 64; }
    gemm_body<0,0,1>(A, 256, Wt, nullptr, nullptr, 0, C, ldc, 256,
                     blockIdx.y * 64, col0, Alds, Wlds);
}

// ---------------- packed: flash attention (z<4) + KNN gather (z>=4) ----------------
// softmax in base-2 (log2e folded into Q weights); P packed via v_cvt_pk_bf16_f32
// into b64 LDS writes with key-permuted layout (V staged with matching permutation).
__global__ __launch_bounds__(256) void attn_gather(
    const unsigned short* __restrict__ Qp, int ldq,
    const unsigned short* __restrict__ Kp, int ldk,
    const unsigned short* __restrict__ Vp, int ldv,
    unsigned short* __restrict__ Op, float* __restrict__ Lp,
    const unsigned short* __restrict__ P, int ldp,
    const unsigned short* __restrict__ Base, int ldb,
    const float* __restrict__ gbias, const int* __restrict__ idx,
    unsigned short* __restrict__ gout, int ldgo)
{
    __shared__ unsigned short Klds[64][40];
    __shared__ __align__(16) unsigned short Vt[32][72];
    __shared__ __align__(16) unsigned short Plds[4][16][72];
    int tid = threadIdx.x, wid = tid >> 6, lane = tid & 63;

    if (blockIdx.z >= 4) {
        // ---- gather branch ----
        int gbid = blockIdx.x + 32 * (blockIdx.y + 8 * (blockIdx.z - 4));
        int q = gbid * 4 + wid;
        int b = q >> 11;
        int c = lane * 4;
        ushort4 bu = *(const ushort4*)(Base + (size_t)q * ldb + c);
        float4 bi = *(const float4*)(gbias + c);
        float bsx = bf2f(bu.x) + bi.x, bsy = bf2f(bu.y) + bi.y;
        float bsz = bf2f(bu.z) + bi.z, bsw = bf2f(bu.w) + bi.w;
        float4 acc = make_float4(-3e38f, -3e38f, -3e38f, -3e38f);
        const int* ip = idx + (size_t)q * 8;
        #pragma unroll
        for (int k = 0; k < 8; ++k) {
            int j = ip[k];
            ushort4 pu = *(const ushort4*)(P + ((size_t)(b * NKVC + j)) * ldp + c);
            float t;
            t = bsx + bf2f(pu.x); t = t > 0.f ? t : 0.2f * t; acc.x = fmaxf(acc.x, t);
            t = bsy + bf2f(pu.y); t = t > 0.f ? t : 0.2f * t; acc.y = fmaxf(acc.y, t);
            t = bsz + bf2f(pu.z); t = t > 0.f ? t : 0.2f * t; acc.z = fmaxf(acc.z, t);
            t = bsw + bf2f(pu.w); t = t > 0.f ? t : 0.2f * t; acc.w = fmaxf(acc.w, t);
        }
        ushort4 o;
        o.x = f2bf(acc.x); o.y = f2bf(acc.y); o.z = f2bf(acc.z); o.w = f2bf(acc.w);
        *(ushort4*)(gout + (size_t)q * ldgo + c) = o;
        return;
    }

    // ---- attention branch (KV-split x2, fixed-max softmax, base-2) ----
    int zc = blockIdx.z, bb = zc >> 1, ck = zc & 1;
    int h = blockIdx.y;
    int hoff = h * 32;
    int lm = lane & 15, quad = lane >> 4;
    size_t qbase  = (size_t)bb * NQC;
    size_t kvbase = (size_t)bb * NKVC;
    int q0 = blockIdx.x * 64 + wid * 16;

    bfrag aq = *(const bfrag*)(Qp + (qbase + q0 + lm) * (size_t)ldq + hoff + quad * 8);

    float l_r[4] = {0.f, 0.f, 0.f, 0.f};
    ffrag oacc[2];
    oacc[0] = (ffrag){0.f, 0.f, 0.f, 0.f};
    oacc[1] = (ffrag){0.f, 0.f, 0.f, 0.f};

    const int kkey = tid >> 2, kd0 = (tid & 3) * 8;
    const int vkey = tid & 63, vd0 = (tid >> 6) * 8;
    const int vcol = ((vkey & 15) << 2) | (vkey >> 4);   // matches P perm: key = (c&3)*16 + (c>>2)
    const unsigned short* kg0 = Kp + (kvbase + kkey) * (size_t)ldk + hoff + kd0;
    const unsigned short* vg0 = Vp + (kvbase + vkey) * (size_t)ldv + hoff + vd0;

    for (int kt = ck * 16; kt < ck * 16 + 16; ++kt) {
        us8 kv = *(const us8*)(kg0 + (size_t)kt * 64 * ldk);
        us8 vv = *(const us8*)(vg0 + (size_t)kt * 64 * ldv);
        __syncthreads();
        *(us8*)&Klds[kkey][kd0] = kv;
        #pragma unroll
        for (int i = 0; i < 8; ++i) Vt[vd0 + i][vcol] = vv[i];
        __syncthreads();

        ffrag sacc[4];
        #pragma unroll
        for (int t = 0; t < 4; ++t) {
            bfrag bk = *(const bfrag*)&Klds[t*16 + lm][quad * 8];
            sacc[t] = __builtin_amdgcn_mfma_f32_16x16x32_bf16(
                aq, bk, (ffrag){0.f,0.f,0.f,0.f}, 0, 0, 0);
        }

        #pragma unroll
        for (int r = 0; r < 4; ++r) {
            float p0 = fexp2(sacc[0][r]), p1 = fexp2(sacc[1][r]);
            float p2 = fexp2(sacc[2][r]), p3 = fexp2(sacc[3][r]);
            l_r[r] += (p0 + p1) + (p2 + p3);
            unsigned u0 = cvt_pk_bf16(p0, p1);
            unsigned u1 = cvt_pk_bf16(p2, p3);
            *(uint2*)&Plds[wid][quad*4 + r][lm << 2] = make_uint2(u0, u1);
        }
        asm volatile("s_waitcnt lgkmcnt(0)" ::: "memory");  // wave-private P RAW

        #pragma unroll
        for (int kc = 0; kc < 2; ++kc) {
            bfrag ap = *(const bfrag*)&Plds[wid][lm][kc*32 + quad*8];
            #pragma unroll
            for (int nt = 0; nt < 2; ++nt) {
                bfrag bv = *(const bfrag*)&Vt[nt*16 + lm][kc*32 + quad*8];
                oacc[nt] = __builtin_amdgcn_mfma_f32_16x16x32_bf16(
                    ap, bv, oacc[nt], 0, 0, 0);
            }
        }
    }
    #pragma unroll
    for (int nt = 0; nt < 2; ++nt)
        #pragma unroll
        for (int r = 0; r < 4; ++r)
            Op[((size_t)ck * 4096 + qbase + q0 + quad*4 + r) * 256 + hoff + nt*16 + lm]
                = f2bf(oacc[nt][r]);
    #pragma unroll
    for (int r = 0; r < 4; ++r) {
        float l = l_r[r];
        l += __shfl_xor(l, 1);
        l += __shfl_xor(l, 2);
        l += __shfl_xor(l, 4);
        l += __shfl_xor(l, 8);
        if (lm == 0)
            Lp[((size_t)ck * 4096 + qbase + q0 + quad*4 + r) * 8 + h] = l;
    }
}

extern "C" void kernel_launch(void* const* d_in, const int* in_sizes, int n_in,
                              void* d_out, int out_size, void* d_ws, size_t ws_size,
                              hipStream_t stream) {
    const float* q_in   = (const float*)d_in[0];
    const float* v_in   = (const float*)d_in[1];
    const int*   idx_s  = (const int*)d_in[4];
    const int*   idx_x  = (const int*)d_in[5];
    const float* n1g = (const float*)d_in[6],  *n1b = (const float*)d_in[7];
    const float* nqg = (const float*)d_in[8],  *nqb = (const float*)d_in[9];
    const float* nvg = (const float*)d_in[10], *nvb = (const float*)d_in[11];
    const float* n2g = (const float*)d_in[12], *n2b = (const float*)d_in[13];
    const float* sa_qkv_w  = (const float*)d_in[14];
    const float* sa_proj_w = (const float*)d_in[15];
    const float* sa_proj_b = (const float*)d_in[16];
    const float* ca_q_w    = (const float*)d_in[17];
    const float* ca_kv_w   = (const float*)d_in[18];
    const float* ca_proj_w = (const float*)d_in[19];
    const float* ca_proj_b = (const float*)d_in[20];
    const float* fc1_w = (const float*)d_in[21], *fc1_b = (const float*)d_in[22];
    const float* fc2_w = (const float*)d_in[23], *fc2_b = (const float*)d_in[24];
    const float* knn_w   = (const float*)d_in[25], *knn_b   = (const float*)d_in[26];
    const float* merge_w = (const float*)d_in[27], *merge_b = (const float*)d_in[28];
    const float* knnx_w  = (const float*)d_in[29], *knnx_b  = (const float*)d_in[30];
    const float* mergex_w = (const float*)d_in[31], *mergex_b = (const float*)d_in[32];
    float* out = (float*)d_out;

    unsigned short* A1      = (unsigned short*)d_ws;           // 4096x1280 bf16
    unsigned short* A2      = A1;                              // 4096x512 (stage2 overlay)
    unsigned short* A3      = A1 + (size_t)4096 * 512;         // 4096x768 (stage2 overlay)
    unsigned short* Hb      = A1;                              // 4096x1024 (stage3 overlay)
    unsigned short* KN      = A1 + (size_t)4096 * 1280;        // 4096x256 knn_out (CC+256 view)
    unsigned short* CC      = KN;                              // 4096x512 [unused | knn_out]
    unsigned short* XB      = CC + (size_t)4096 * 512;         // 4096x256 LN out
    unsigned short* NVB     = XB + (size_t)4096 * 256;         // 4096x256 LN(v)
    unsigned short* WT      = NVB + (size_t)4096 * 256;        // weights, 1572864 us
    unsigned short* WT1     = WT;
    unsigned short* projbf  = WT + 327680;                     // proj bf16 [k][n] linear
    unsigned short* WTmerge = WT + 393216;
    unsigned short* WT2     = WT + 524288;
    unsigned short* WT3     = WT + 655360;
    unsigned short* projxbf = WT + 851968;                     // projx bf16 [k][n] linear
    unsigned short* WTmergex= WT + 917504;
    unsigned short* WTfc1   = WT + 1048576;
    unsigned short* WTfc2   = WT + 1310720;
    unsigned short* Opart   = WT + 1572864;                    // [2][4096][256] bf16
    float* Lpart = (float*)(Opart + (size_t)2 * 4096 * 256);   // [2][4096][8]  f32
    unsigned short* WTf1 = (unsigned short*)(Lpart + (size_t)2 * 4096 * 8);  // [256][256]
    unsigned short* WTfx = WTf1 + 65536;                                     // [256][256]
    float* bf1 = (float*)(WTfx + 65536);                       // folded bias stage1 [256]
    float* bfx = bf1 + 256;                                    // folded bias stage2 [256]

    dim3 blk(256), blk8(512);
    dim3 gAG(NQC / 64, 8, 8);     // z<4: attn (b*2+ck); z>=4: gather

    // prep: tiled-transpose weights + copies + LN(q) + LN(v) + bias folds
    prep_w<<<dim3(2530), blk, 0, stream>>>(sa_qkv_w, knn_w, sa_proj_w, merge_w,
        ca_q_w, knnx_w, ca_kv_w, ca_proj_w, mergex_w, fc1_w, fc2_w, WT,
        q_in, n1g, n1b, XB,
        v_in, nvg, nvb, NVB,
        sa_proj_b, merge_b, bf1,
        ca_proj_b, mergex_b, bfx);

    // ---- stage 1 ----
    gemm_qkv_fold<<<dim3(20,66), blk, 0, stream>>>(XB, WT1, A1,
        WTmerge, projbf, WTf1, WTmergex, projxbf, WTfx);                            // [qkv|P|Base] + folds
    attn_gather<<<gAG, blk, 0, stream>>>(A1, 1280, A1+256, 1280, A1+512, 1280,
        Opart, Lpart, A1+768, 1280, A1+1024, 1280, knn_b, idx_s, CC+256, 512);
    gemm_mln<<<dim3(256), blk8, 0, stream>>>(Opart, Lpart, CC+256,
        WTf1, WTmerge+256, bf1, q_in, out, nqg, nqb, XB);                           // q += merge; XB = LN(q)

    // ---- stage 2 ----
    gemm64_dual<<<dim3(20,64), blk, 0, stream>>>(XB, NVB, WT2, WT3, A2, A3);        // both projections
    attn_gather<<<gAG, blk, 0, stream>>>(A2, 512, A3, 768, A3+256, 768,
        Opart, Lpart, A3+512, 768, A2+256, 512, knnx_b, idx_x, CC+256, 512);
    gemm_mln<<<dim3(256), blk8, 0, stream>>>(Opart, Lpart, CC+256,
        WTfx, WTmergex+256, bfx, out, out, n2g, n2b, XB);                           // q += mergex; XB = LN(q)

    // ---- stage 3 ----
    gemm64<1,0,1><<<dim3(16,64), blk, 0, stream>>>(XB, 256, WTfc1,
        fc1_b, nullptr, 0, Hb, 1024, 256);                                          // gelu(LN(q)@fc1+b)
    gemm64x8<0,1,0><<<dim3(4,64), blk8, 0, stream>>>(Hb, 1024, WTfc2,
        fc2_b, out, 256, out, 256, 1024);                                           // q += fc2
}